// Round 2
// baseline (4832.018 us; speedup 1.0000x reference)
//
#include <hip/hip_runtime.h>
#include <math.h>

// ---------------------------------------------------------------------------
// CapsuleNet forward, fp32 (round 2: fit workspace under 256 MiB).
// Peak footprint = h + wt + wt1 + C = 62,476,544 floats = 238.3 MiB.
// After prim_gemm, h is dead; u/vbuf/msk/d1/d2 alias the old h region.
// ---------------------------------------------------------------------------

#define NB 512

// workspace layout (floats)
#define OFF_H    0L            // 512*20*20*256 = 52428800 (dead after prim_gemm)
#define OFF_WT   52428800L     // 81*256*256    = 5308416
#define OFF_WT1  57737216L     // 81*256        = 20736
#define OFF_C    57757952L     // 18432*256     = 4718592
#define WS_FLOATS 62476544L    // 238.3 MiB peak

// aliased into the old h region (all << 52428800 floats):
#define OFF_U    0L            // 512*1152*8 = 4718592
#define OFF_V    4718592L      // 512*10*16  = 81920
#define OFF_MSK  4800512L      // 512*160    = 81920
#define OFF_D1   4882432L      // 512*512    = 262144
#define OFF_D2   5144576L      // 512*1024   = 524288

// --------------------------------------------------------------------------
__global__ void transpose_w1(const float* __restrict__ w, float* __restrict__ wt) {
    int i = blockIdx.x * 256 + threadIdx.x;          // 81*256 = 20736 exact
    int k = i >> 8, oc = i & 255;
    wt[i] = w[oc * 81 + k];
}

__global__ void transpose_pw(const float* __restrict__ w, float* __restrict__ wt) {
    int i = blockIdx.x * 256 + threadIdx.x;          // 5308416 exact
    int oc = i & 255;
    int r = i >> 8;                                   // tap*256 + ic
    int ic = r & 255;
    int tap = r >> 8;
    wt[i] = w[(oc * 256 + ic) * 81 + tap];
}

// --------------------------------------------------------------------------
// conv1: x[b][28][28] * w[oc][9][9] -> h[b][y][x][oc] (NHWC), ReLU
__global__ __launch_bounds__(448) void conv1_k(const float* __restrict__ x,
                                               const float* __restrict__ wt1,
                                               const float* __restrict__ bias,
                                               float* __restrict__ h) {
    __shared__ float xs[784];
    int b = blockIdx.x;
    int tid = threadIdx.x;
    for (int i = tid; i < 784; i += 448) xs[i] = x[b * 784 + i];
    __syncthreads();
    if (tid >= 400) return;
    int oy = tid / 20, ox = tid - oy * 20;
    int xbase = oy * 28 + ox;
    float* hp = h + ((b * 20 + oy) * 20 + ox) * 256;
    for (int ocg = 0; ocg < 16; ++ocg) {
        int oc0 = ocg * 16;
        float acc[16];
#pragma unroll
        for (int j = 0; j < 16; ++j) acc[j] = bias[oc0 + j];
#pragma unroll
        for (int ky = 0; ky < 9; ++ky) {
#pragma unroll
            for (int kx = 0; kx < 9; ++kx) {
                float xv = xs[xbase + ky * 28 + kx];
                const float* wr = wt1 + (ky * 9 + kx) * 256 + oc0;
#pragma unroll
                for (int j = 0; j < 16; ++j) acc[j] = fmaf(wr[j], xv, acc[j]);
            }
        }
#pragma unroll
        for (int j = 0; j < 16; ++j) acc[j] = fmaxf(acc[j], 0.f);
#pragma unroll
        for (int j4 = 0; j4 < 4; ++j4) {
            float4 o = make_float4(acc[j4*4], acc[j4*4+1], acc[j4*4+2], acc[j4*4+3]);
            *(float4*)(hp + oc0 + j4 * 4) = o;
        }
    }
}

// --------------------------------------------------------------------------
// prim conv implicit GEMM: C[M=18432][256] = A[M][20736] * B[20736][256] + bias
// A[m][k] = h[b, 2*oy+ky, 2*ox+kx, ic], k = (ky*9+kx)*256+ic (tap-major)
__global__ __launch_bounds__(256, 2) void prim_gemm(const float* __restrict__ h,
                                                    const float* __restrict__ wt,
                                                    const float* __restrict__ bias,
                                                    float* __restrict__ C) {
    __shared__ float As[32][132];
    __shared__ float Bs[32][68];
    int tid = threadIdx.x;
    int bx = blockIdx.x;
    int nt = bx & 3, mt = bx >> 2;
    int n0 = nt * 64;
    int tx = tid & 15, ty = tid >> 4;
    int f4 = tid & 7;

    int base0[4], mloc[4];
#pragma unroll
    for (int r = 0; r < 4; ++r) {
        int ml = r * 32 + (tid >> 3);
        mloc[r] = ml;
        int m = mt * 128 + ml;
        int b = m / 36; int pos = m - b * 36;
        int oy = pos / 6; int ox = pos - oy * 6;
        base0[r] = ((b * 20 + 2 * oy) * 20 + 2 * ox) * 256;
    }

    float4 aReg[4]; float4 bReg[2];
    auto loadA = [&](int kb) {
        int tap = kb >> 3;
        int ic0 = (kb & 7) << 5;
        int ky = tap / 9; int kx = tap - ky * 9;
        int koff = (ky * 20 + kx) * 256 + ic0 + (f4 << 2);
#pragma unroll
        for (int r = 0; r < 4; ++r)
            aReg[r] = *(const float4*)(h + base0[r] + koff);
    };
    auto loadB = [&](int kb) {
#pragma unroll
        for (int r = 0; r < 2; ++r) {
            int idx = r * 256 + tid;
            int kk = idx >> 4, nn4 = idx & 15;
            bReg[r] = *(const float4*)(wt + (kb * 32 + kk) * 256 + n0 + nn4 * 4);
        }
    };

    float acc[8][4];
#pragma unroll
    for (int i = 0; i < 8; ++i)
#pragma unroll
        for (int j = 0; j < 4; ++j) acc[i][j] = 0.f;

    loadA(0); loadB(0);
    for (int kb = 0; kb < 648; ++kb) {
        __syncthreads();
        int k4 = f4 * 4;
#pragma unroll
        for (int r = 0; r < 4; ++r) {
            As[k4 + 0][mloc[r]] = aReg[r].x;
            As[k4 + 1][mloc[r]] = aReg[r].y;
            As[k4 + 2][mloc[r]] = aReg[r].z;
            As[k4 + 3][mloc[r]] = aReg[r].w;
        }
#pragma unroll
        for (int r = 0; r < 2; ++r) {
            int idx = r * 256 + tid;
            int kk = idx >> 4, nn4 = idx & 15;
            *(float4*)&Bs[kk][nn4 * 4] = bReg[r];
        }
        __syncthreads();
        if (kb + 1 < 648) { loadA(kb + 1); loadB(kb + 1); }
#pragma unroll 8
        for (int kk = 0; kk < 32; ++kk) {
            float4 a0 = *(const float4*)&As[kk][ty * 8];
            float4 a1 = *(const float4*)&As[kk][ty * 8 + 4];
            float4 bv = *(const float4*)&Bs[kk][tx * 4];
            float a[8] = {a0.x, a0.y, a0.z, a0.w, a1.x, a1.y, a1.z, a1.w};
            float bb[4] = {bv.x, bv.y, bv.z, bv.w};
#pragma unroll
            for (int i = 0; i < 8; ++i)
#pragma unroll
                for (int j = 0; j < 4; ++j)
                    acc[i][j] = fmaf(a[i], bb[j], acc[i][j]);
        }
    }
    float4 bi = *(const float4*)(bias + n0 + tx * 4);
#pragma unroll
    for (int i = 0; i < 8; ++i) {
        int m = mt * 128 + ty * 8 + i;
        float4 o = make_float4(acc[i][0] + bi.x, acc[i][1] + bi.y,
                               acc[i][2] + bi.z, acc[i][3] + bi.w);
        *(float4*)(C + m * 256 + n0 + tx * 4) = o;
    }
}

// --------------------------------------------------------------------------
// squash over the 8 capsule dims: C[(b*36+pos)][oc] -> u[b][n][i]
__global__ void squash_k(const float* __restrict__ C, float* __restrict__ u) {
    int t = blockIdx.x * 256 + threadIdx.x;          // 589824 exact
    int b = t / 1152; int n = t - b * 1152;
    int ci = n / 36; int pos = n - ci * 36;
    const float* src = C + (b * 36 + pos) * 256 + ci;
    float v[8]; float sn = 0.f;
#pragma unroll
    for (int i = 0; i < 8; ++i) { v[i] = src[i * 32]; sn = fmaf(v[i], v[i], sn); }
    float scale = (sn / (1.f + sn)) / sqrtf(sn);
    float* dst = u + t * 8;
    float4 o0 = make_float4(v[0]*scale, v[1]*scale, v[2]*scale, v[3]*scale);
    float4 o1 = make_float4(v[4]*scale, v[5]*scale, v[6]*scale, v[7]*scale);
    *(float4*)(dst) = o0;
    *(float4*)(dst + 4) = o1;
}

// --------------------------------------------------------------------------
// routing: one block per (c,b). 384 threads; each owns 3 route nodes,
// priors kept in registers. 3 iterations of softmax-weighted agreement.
__global__ __launch_bounds__(384) void routing_k(const float* __restrict__ u,
                                                 const float* __restrict__ rw,
                                                 float* __restrict__ vbuf) {
    int c = blockIdx.x >> 9;
    int b = blockIdx.x & 511;
    int tid = threadIdx.x;
    int wid = tid >> 6;
    int lane = tid & 63;
    __shared__ float wred[6][20];   // cols 0..15 = ps, 16 = expsum, 17 = max

    float pr[3][16];
#pragma unroll
    for (int r = 0; r < 3; ++r) {
        int n = tid + r * 384;
        const float4* up = (const float4*)(u + (b * 1152 + n) * 8);
        float4 ua = up[0], ub = up[1];
        float uu[8] = {ua.x, ua.y, ua.z, ua.w, ub.x, ub.y, ub.z, ub.w};
        const float4* wp = (const float4*)(rw + (c * 1152 + n) * 128);
#pragma unroll
        for (int o = 0; o < 16; ++o) pr[r][o] = 0.f;
#pragma unroll
        for (int i = 0; i < 8; ++i) {
#pragma unroll
            for (int o4 = 0; o4 < 4; ++o4) {
                float4 w4 = wp[i * 4 + o4];
                pr[r][o4*4+0] = fmaf(uu[i], w4.x, pr[r][o4*4+0]);
                pr[r][o4*4+1] = fmaf(uu[i], w4.y, pr[r][o4*4+1]);
                pr[r][o4*4+2] = fmaf(uu[i], w4.z, pr[r][o4*4+2]);
                pr[r][o4*4+3] = fmaf(uu[i], w4.w, pr[r][o4*4+3]);
            }
        }
    }

    float l0 = 0.f, l1 = 0.f, l2 = 0.f;
    float vout[16];
    for (int it = 0; it < 3; ++it) {
        float lm = fmaxf(fmaxf(l0, l1), l2);
#pragma unroll
        for (int m = 32; m >= 1; m >>= 1) lm = fmaxf(lm, __shfl_xor(lm, m));
        if (lane == 0) wred[wid][17] = lm;
        __syncthreads();
        float maxv = wred[0][17];
#pragma unroll
        for (int w = 1; w < 6; ++w) maxv = fmaxf(maxv, wred[w][17]);

        float e0 = expf(l0 - maxv), e1 = expf(l1 - maxv), e2 = expf(l2 - maxv);
        float red[17];
#pragma unroll
        for (int o = 0; o < 16; ++o)
            red[o] = fmaf(e0, pr[0][o], fmaf(e1, pr[1][o], e2 * pr[2][o]));
        red[16] = e0 + e1 + e2;
#pragma unroll
        for (int o = 0; o < 17; ++o) {
#pragma unroll
            for (int m = 32; m >= 1; m >>= 1) red[o] += __shfl_xor(red[o], m);
        }
        __syncthreads();
        if (lane == 0) {
#pragma unroll
            for (int o = 0; o < 17; ++o) wred[wid][o] = red[o];
        }
        __syncthreads();
        float sv[17];
#pragma unroll
        for (int o = 0; o < 17; ++o) {
            float tacc = wred[0][o];
#pragma unroll
            for (int w = 1; w < 6; ++w) tacc += wred[w][o];
            sv[o] = tacc;
        }
        float inv = 1.f / sv[16];
        float sn = 0.f;
#pragma unroll
        for (int o = 0; o < 16; ++o) { float s = sv[o] * inv; sn = fmaf(s, s, sn); }
        float scale = (sn / (1.f + sn)) / sqrtf(sn);
#pragma unroll
        for (int o = 0; o < 16; ++o) vout[o] = sv[o] * inv * scale;

        if (it < 2) {
            float d0 = 0.f, d1 = 0.f, d2 = 0.f;
#pragma unroll
            for (int o = 0; o < 16; ++o) {
                d0 = fmaf(pr[0][o], vout[o], d0);
                d1 = fmaf(pr[1][o], vout[o], d1);
                d2 = fmaf(pr[2][o], vout[o], d2);
            }
            l0 += d0; l1 += d1; l2 += d2;
        }
    }
    if (tid < 16) vbuf[(b * 10 + c) * 16 + tid] = vout[tid];
}

// --------------------------------------------------------------------------
// classes / argmax / y_pred / masked
__global__ void mask_k(const float* __restrict__ vbuf, float* __restrict__ out,
                       float* __restrict__ masked) {
    int b = blockIdx.x * 256 + threadIdx.x;
    if (b >= 512) return;
    const float* vp = vbuf + b * 160;
    float cls[10]; int best = 0; float bv = -1.f;
#pragma unroll
    for (int cc = 0; cc < 10; ++cc) {
        float sn = 0.f;
#pragma unroll
        for (int o = 0; o < 16; ++o) { float v = vp[cc * 16 + o]; sn = fmaf(v, v, sn); }
        cls[cc] = sqrtf(sn);
        if (cls[cc] > bv) { bv = cls[cc]; best = cc; }
    }
#pragma unroll
    for (int cc = 0; cc < 10; ++cc) {
        out[b * 10 + cc] = (cc == best) ? 1.f : 0.f;          // y_pred
        out[406528 + b * 10 + cc] = cls[cc];                  // classes
    }
#pragma unroll
    for (int cc = 0; cc < 10; ++cc) {
        float keep = (cc == best) ? 1.f : 0.f;
#pragma unroll
        for (int o = 0; o < 16; ++o)
            masked[b * 160 + cc * 16 + o] = keep * vp[cc * 16 + o];
    }
}

// --------------------------------------------------------------------------
// decoder GEMM: C[M][N] = act(A[M][K] * B[K][N] + bias). BM=BN=64, BK=16.
template <int ACT>
__global__ __launch_bounds__(256) void dec_gemm(const float* __restrict__ A,
                                                const float* __restrict__ Bw,
                                                const float* __restrict__ bias,
                                                float* __restrict__ C,
                                                int M, int N, int K) {
    __shared__ float As[16][68];
    __shared__ float Bs[16][68];
    int ntiles = (N + 63) >> 6;
    int mt = blockIdx.x / ntiles, nt = blockIdx.x - mt * ntiles;
    int m0 = mt * 64, n0 = nt * 64;
    int tid = threadIdx.x;
    int tx = tid & 15, ty = tid >> 4;
    int am = tid >> 2, ak = (tid & 3) * 4;
    int bk = tid >> 4, bn = (tid & 15) * 4;
    float acc[4][4];
#pragma unroll
    for (int i = 0; i < 4; ++i)
#pragma unroll
        for (int j = 0; j < 4; ++j) acc[i][j] = 0.f;

    for (int k0 = 0; k0 < K; k0 += 16) {
        float4 av = *(const float4*)(A + (m0 + am) * K + k0 + ak);
        float4 bv = make_float4(0.f, 0.f, 0.f, 0.f);
        if (n0 + bn < N) bv = *(const float4*)(Bw + (k0 + bk) * N + n0 + bn);
        __syncthreads();
        As[ak + 0][am] = av.x;
        As[ak + 1][am] = av.y;
        As[ak + 2][am] = av.z;
        As[ak + 3][am] = av.w;
        *(float4*)&Bs[bk][bn] = bv;
        __syncthreads();
#pragma unroll
        for (int kk = 0; kk < 16; ++kk) {
            float4 a = *(const float4*)&As[kk][ty * 4];
            float4 bb = *(const float4*)&Bs[kk][tx * 4];
            float aa[4] = {a.x, a.y, a.z, a.w};
            float bbb[4] = {bb.x, bb.y, bb.z, bb.w};
#pragma unroll
            for (int i = 0; i < 4; ++i)
#pragma unroll
                for (int j = 0; j < 4; ++j)
                    acc[i][j] = fmaf(aa[i], bbb[j], acc[i][j]);
        }
    }
#pragma unroll
    for (int i = 0; i < 4; ++i) {
        int m = m0 + ty * 4 + i;
#pragma unroll
        for (int j = 0; j < 4; ++j) {
            int n = n0 + tx * 4 + j;
            if (n < N) {
                float v = acc[i][j] + bias[n];
                if (ACT == 0) v = fmaxf(v, 0.f);
                else          v = 1.f / (1.f + expf(-v));
                C[m * N + n] = v;
            }
        }
    }
}

// --------------------------------------------------------------------------
extern "C" void kernel_launch(void* const* d_in, const int* in_sizes, int n_in,
                              void* d_out, int out_size, void* d_ws, size_t ws_size,
                              hipStream_t stream) {
    const float* x   = (const float*)d_in[0];
    const float* w1  = (const float*)d_in[1];
    const float* b1  = (const float*)d_in[2];
    const float* pw  = (const float*)d_in[3];
    const float* pb  = (const float*)d_in[4];
    const float* rw  = (const float*)d_in[5];
    const float* dw1 = (const float*)d_in[6];
    const float* db1 = (const float*)d_in[7];
    const float* dw2 = (const float*)d_in[8];
    const float* db2 = (const float*)d_in[9];
    const float* dw3 = (const float*)d_in[10];
    const float* db3 = (const float*)d_in[11];
    float* out = (float*)d_out;
    float* ws  = (float*)d_ws;
    if (ws_size < WS_FLOATS * sizeof(float)) return;  // 238.3 MiB needed

    float* h    = ws + OFF_H;
    float* wt   = ws + OFF_WT;
    float* wt1  = ws + OFF_WT1;
    float* Cbuf = ws + OFF_C;
    // aliases into dead h region:
    float* u    = ws + OFF_U;
    float* vbuf = ws + OFF_V;
    float* msk  = ws + OFF_MSK;
    float* d1   = ws + OFF_D1;
    float* d2   = ws + OFF_D2;

    transpose_w1<<<81, 256, 0, stream>>>(w1, wt1);
    transpose_pw<<<20736, 256, 0, stream>>>(pw, wt);
    conv1_k<<<NB, 448, 0, stream>>>(x, wt1, b1, h);
    prim_gemm<<<576, 256, 0, stream>>>(h, wt, pb, Cbuf);
    squash_k<<<2304, 256, 0, stream>>>(Cbuf, u);       // h dead from here on
    routing_k<<<5120, 384, 0, stream>>>(u, rw, vbuf);
    mask_k<<<2, 256, 0, stream>>>(vbuf, out, msk);
    dec_gemm<0><<<64, 256, 0, stream>>>(msk, dw1, db1, d1, 512, 512, 160);
    dec_gemm<0><<<128, 256, 0, stream>>>(d1, dw2, db2, d2, 512, 1024, 512);
    dec_gemm<1><<<104, 256, 0, stream>>>(d2, dw3, db3, out + 5120, 512, 784, 1024);
}

// Round 3
// 2547.726 us; speedup vs baseline: 1.8966x; 1.8966x over previous
//
#include <hip/hip_runtime.h>
#include <math.h>

// ---------------------------------------------------------------------------
// CapsuleNet forward (round 3): prim conv as fp16-split MFMA implicit GEMM.
// C = Ah*Bh + Ah*Bl + Al*Bh  (fp16 hi/lo split, ~2^-22 relative error).
// conv1 emits h as fp16 hi/lo NHWC; split_pw emits B^T [oc][k] fp16 hi/lo.
// Everything else (squash/routing/mask/decoder) unchanged from round 2.
// ---------------------------------------------------------------------------

typedef _Float16 h16;
typedef h16 frag8 __attribute__((ext_vector_type(8)));    // 8 halves = 16 B
typedef float f32x4 __attribute__((ext_vector_type(4)));

// workspace layout (BYTE offsets). Peak = 249,906,176 B (same as round 2).
#define OFFB_HHI   0L              // 52428800 halves = 104857600 B
#define OFFB_HLO   104857600L     // 52428800 halves
#define OFFB_WTHI  209715200L     // 5308416 halves = 10616832 B
#define OFFB_WTLO  220332032L     // 5308416 halves
#define OFFB_WT1   230948864L     // 20736 floats = 82944 B
#define OFFB_C     231031808L     // 4718592 floats = 18874368 B -> end 249906176
#define WS_BYTES   249906176L
// aliased into dead h region after prim_gemm:
#define OFFB_U     0L             // 4718592 floats
#define OFFB_V     18874368L      // 81920 floats
#define OFFB_MSK   19202048L      // 81920 floats
#define OFFB_D1    19529728L      // 262144 floats
#define OFFB_D2    20578304L      // 524288 floats

// --------------------------------------------------------------------------
__global__ void transpose_w1(const float* __restrict__ w, float* __restrict__ wt) {
    int i = blockIdx.x * 256 + threadIdx.x;          // 20736 exact
    int k = i >> 8, oc = i & 255;
    wt[i] = w[oc * 81 + k];
}

// prim weights -> B^T fp16 hi/lo: wt[oc][k], k = tap*256+ic
__global__ void split_pw(const float* __restrict__ w,
                         h16* __restrict__ whi, h16* __restrict__ wlo) {
    int i = blockIdx.x * 256 + threadIdx.x;          // 5308416 exact
    int oc = i / 20736; int r = i - oc * 20736;
    int tap = r >> 8; int ic = r & 255;
    float v = w[(oc * 256 + ic) * 81 + tap];
    h16 hi = (h16)v;
    whi[i] = hi;
    wlo[i] = (h16)(v - (float)hi);
}

// --------------------------------------------------------------------------
// conv1: x[b][28][28] * w -> h fp16 hi/lo, NHWC [b][y][x][oc], ReLU
__global__ __launch_bounds__(448) void conv1_k(const float* __restrict__ x,
                                               const float* __restrict__ wt1,
                                               const float* __restrict__ bias,
                                               h16* __restrict__ hhi,
                                               h16* __restrict__ hlo) {
    __shared__ float xs[784];
    int b = blockIdx.x;
    int tid = threadIdx.x;
    for (int i = tid; i < 784; i += 448) xs[i] = x[b * 784 + i];
    __syncthreads();
    if (tid >= 400) return;
    int oy = tid / 20, ox = tid - oy * 20;
    int xbase = oy * 28 + ox;
    long hb = ((long)(b * 20 + oy) * 20 + ox) * 256;
    for (int ocg = 0; ocg < 16; ++ocg) {
        int oc0 = ocg * 16;
        float acc[16];
#pragma unroll
        for (int j = 0; j < 16; ++j) acc[j] = bias[oc0 + j];
#pragma unroll
        for (int ky = 0; ky < 9; ++ky) {
#pragma unroll
            for (int kx = 0; kx < 9; ++kx) {
                float xv = xs[xbase + ky * 28 + kx];
                const float* wr = wt1 + (ky * 9 + kx) * 256 + oc0;
#pragma unroll
                for (int j = 0; j < 16; ++j) acc[j] = fmaf(wr[j], xv, acc[j]);
            }
        }
        frag8 h0, h1, l0, l1;
#pragma unroll
        for (int j = 0; j < 8; ++j) {
            float v0 = fmaxf(acc[j], 0.f);
            float v1 = fmaxf(acc[j + 8], 0.f);
            h16 a = (h16)v0, bb = (h16)v1;
            h0[j] = a; l0[j] = (h16)(v0 - (float)a);
            h1[j] = bb; l1[j] = (h16)(v1 - (float)bb);
        }
        *(frag8*)(hhi + hb + oc0)     = h0;
        *(frag8*)(hhi + hb + oc0 + 8) = h1;
        *(frag8*)(hlo + hb + oc0)     = l0;
        *(frag8*)(hlo + hb + oc0 + 8) = l1;
    }
}

// --------------------------------------------------------------------------
// prim conv MFMA GEMM: C[18432][256] = A[18432][20736] * B[20736][256] + bias
// A[m][k] = h[b, 2oy+ky, 2ox+kx, ic] fp16 hi/lo; B^T stored [oc][k] hi/lo.
// BM=128 BN=64 BK=32; 4 waves in 2x2; wave tile 64x32 (4x2 frags 16x16x32).
// 3 MFMA passes: hh, hl, lh.
#define LDK 40   // padded LDS k-stride (halves): 80 B row -> conflict-free
__global__ __launch_bounds__(256, 2) void prim_gemm_mfma(
        const h16* __restrict__ Ahi, const h16* __restrict__ Alo,
        const h16* __restrict__ Bhi, const h16* __restrict__ Blo,
        const float* __restrict__ bias, float* __restrict__ C) {
    __shared__ h16 As[2][128][LDK];
    __shared__ h16 Bs[2][64][LDK];
    int tid = threadIdx.x;
    int bx = blockIdx.x;                  // 576 blocks
    int nt = bx & 3, mt = bx >> 2;
    int n0 = nt * 64;

    int wave = tid >> 6;
    int wm = wave >> 1, wn = wave & 1;    // wave tile origin: (wm*64, wn*32)
    int lane = tid & 63;
    int lm = lane & 15, quad = lane >> 4;

    // A staging: thread -> row ra = tid>>1, 16-half segment sa = (tid&1)*16
    int ra = tid >> 1;
    int sa = (tid & 1) * 16;
    int ma = mt * 128 + ra;
    int b = ma / 36, pos = ma - b * 36;
    int oy = pos / 6, ox = pos - oy * 6;
    long abase = ((long)(b * 20 + 2 * oy) * 20 + 2 * ox) * 256 + sa;
    // B staging: row rb = tid>>2, 8-half segment sb = (tid&3)*8
    int rb = tid >> 2;
    int sb = (tid & 3) * 8;
    long bbase = (long)(n0 + rb) * 20736 + sb;

    float4 pa0h, pa1h, pa0l, pa1l, pbh, pbl;
    auto gload = [&](int kb) {
        int tap = kb >> 3;
        int ic0 = (kb & 7) << 5;
        int ky = tap / 9, kx = tap - ky * 9;
        long aoff = abase + (ky * 20 + kx) * 256 + ic0;
        pa0h = *(const float4*)(Ahi + aoff);
        pa1h = *(const float4*)(Ahi + aoff + 8);
        pa0l = *(const float4*)(Alo + aoff);
        pa1l = *(const float4*)(Alo + aoff + 8);
        long boff = bbase + kb * 32;
        pbh = *(const float4*)(Bhi + boff);
        pbl = *(const float4*)(Blo + boff);
    };

    f32x4 acc[4][2];
#pragma unroll
    for (int i = 0; i < 4; ++i)
#pragma unroll
        for (int j = 0; j < 2; ++j) acc[i][j] = (f32x4){0.f, 0.f, 0.f, 0.f};

    gload(0);
    for (int kb = 0; kb < 648; ++kb) {
        __syncthreads();
        *(float4*)&As[0][ra][sa]     = pa0h;
        *(float4*)&As[0][ra][sa + 8] = pa1h;
        *(float4*)&As[1][ra][sa]     = pa0l;
        *(float4*)&As[1][ra][sa + 8] = pa1l;
        *(float4*)&Bs[0][rb][sb]     = pbh;
        *(float4*)&Bs[1][rb][sb]     = pbl;
        __syncthreads();
        if (kb + 1 < 648) gload(kb + 1);

        frag8 ah[4], al[4], bh[2], bl[2];
#pragma unroll
        for (int mi = 0; mi < 4; ++mi) {
            int row = wm * 64 + mi * 16 + lm;
            ah[mi] = *(const frag8*)&As[0][row][quad * 8];
            al[mi] = *(const frag8*)&As[1][row][quad * 8];
        }
#pragma unroll
        for (int ni = 0; ni < 2; ++ni) {
            int col = wn * 32 + ni * 16 + lm;
            bh[ni] = *(const frag8*)&Bs[0][col][quad * 8];
            bl[ni] = *(const frag8*)&Bs[1][col][quad * 8];
        }
#pragma unroll
        for (int mi = 0; mi < 4; ++mi)
#pragma unroll
            for (int ni = 0; ni < 2; ++ni) {
                acc[mi][ni] = __builtin_amdgcn_mfma_f32_16x16x32_f16(
                    ah[mi], bh[ni], acc[mi][ni], 0, 0, 0);
                acc[mi][ni] = __builtin_amdgcn_mfma_f32_16x16x32_f16(
                    ah[mi], bl[ni], acc[mi][ni], 0, 0, 0);
                acc[mi][ni] = __builtin_amdgcn_mfma_f32_16x16x32_f16(
                    al[mi], bh[ni], acc[mi][ni], 0, 0, 0);
            }
    }

    // epilogue: C/D layout col = lane&15, row = quad*4 + reg
#pragma unroll
    for (int ni = 0; ni < 2; ++ni) {
        int n = n0 + wn * 32 + ni * 16 + lm;
        float bv = bias[n];
#pragma unroll
        for (int mi = 0; mi < 4; ++mi) {
            int m = mt * 128 + wm * 64 + mi * 16 + quad * 4;
#pragma unroll
            for (int r = 0; r < 4; ++r)
                C[(long)(m + r) * 256 + n] = acc[mi][ni][r] + bv;
        }
    }
}

// --------------------------------------------------------------------------
// squash over the 8 capsule dims: C[(b*36+pos)][oc] -> u[b][n][i]
__global__ void squash_k(const float* __restrict__ C, float* __restrict__ u) {
    int t = blockIdx.x * 256 + threadIdx.x;          // 589824 exact
    int b = t / 1152; int n = t - b * 1152;
    int ci = n / 36; int pos = n - ci * 36;
    const float* src = C + (b * 36 + pos) * 256 + ci;
    float v[8]; float sn = 0.f;
#pragma unroll
    for (int i = 0; i < 8; ++i) { v[i] = src[i * 32]; sn = fmaf(v[i], v[i], sn); }
    float scale = (sn / (1.f + sn)) / sqrtf(sn);
    float* dst = u + t * 8;
    float4 o0 = make_float4(v[0]*scale, v[1]*scale, v[2]*scale, v[3]*scale);
    float4 o1 = make_float4(v[4]*scale, v[5]*scale, v[6]*scale, v[7]*scale);
    *(float4*)(dst) = o0;
    *(float4*)(dst + 4) = o1;
}

// --------------------------------------------------------------------------
// routing: one block per (c,b). 384 threads; each owns 3 route nodes.
__global__ __launch_bounds__(384) void routing_k(const float* __restrict__ u,
                                                 const float* __restrict__ rw,
                                                 float* __restrict__ vbuf) {
    int c = blockIdx.x >> 9;
    int b = blockIdx.x & 511;
    int tid = threadIdx.x;
    int wid = tid >> 6;
    int lane = tid & 63;
    __shared__ float wred[6][20];

    float pr[3][16];
#pragma unroll
    for (int r = 0; r < 3; ++r) {
        int n = tid + r * 384;
        const float4* up = (const float4*)(u + (b * 1152 + n) * 8);
        float4 ua = up[0], ub = up[1];
        float uu[8] = {ua.x, ua.y, ua.z, ua.w, ub.x, ub.y, ub.z, ub.w};
        const float4* wp = (const float4*)(rw + ((long)c * 1152 + n) * 128);
#pragma unroll
        for (int o = 0; o < 16; ++o) pr[r][o] = 0.f;
#pragma unroll
        for (int i = 0; i < 8; ++i) {
#pragma unroll
            for (int o4 = 0; o4 < 4; ++o4) {
                float4 w4 = wp[i * 4 + o4];
                pr[r][o4*4+0] = fmaf(uu[i], w4.x, pr[r][o4*4+0]);
                pr[r][o4*4+1] = fmaf(uu[i], w4.y, pr[r][o4*4+1]);
                pr[r][o4*4+2] = fmaf(uu[i], w4.z, pr[r][o4*4+2]);
                pr[r][o4*4+3] = fmaf(uu[i], w4.w, pr[r][o4*4+3]);
            }
        }
    }

    float l0 = 0.f, l1 = 0.f, l2 = 0.f;
    float vout[16];
    for (int it = 0; it < 3; ++it) {
        float lm = fmaxf(fmaxf(l0, l1), l2);
#pragma unroll
        for (int m = 32; m >= 1; m >>= 1) lm = fmaxf(lm, __shfl_xor(lm, m));
        if (lane == 0) wred[wid][17] = lm;
        __syncthreads();
        float maxv = wred[0][17];
#pragma unroll
        for (int w = 1; w < 6; ++w) maxv = fmaxf(maxv, wred[w][17]);

        float e0 = expf(l0 - maxv), e1 = expf(l1 - maxv), e2 = expf(l2 - maxv);
        float red[17];
#pragma unroll
        for (int o = 0; o < 16; ++o)
            red[o] = fmaf(e0, pr[0][o], fmaf(e1, pr[1][o], e2 * pr[2][o]));
        red[16] = e0 + e1 + e2;
#pragma unroll
        for (int o = 0; o < 17; ++o) {
#pragma unroll
            for (int m = 32; m >= 1; m >>= 1) red[o] += __shfl_xor(red[o], m);
        }
        __syncthreads();
        if (lane == 0) {
#pragma unroll
            for (int o = 0; o < 17; ++o) wred[wid][o] = red[o];
        }
        __syncthreads();
        float sv[17];
#pragma unroll
        for (int o = 0; o < 17; ++o) {
            float tacc = wred[0][o];
#pragma unroll
            for (int w = 1; w < 6; ++w) tacc += wred[w][o];
            sv[o] = tacc;
        }
        float inv = 1.f / sv[16];
        float sn = 0.f;
#pragma unroll
        for (int o = 0; o < 16; ++o) { float s = sv[o] * inv; sn = fmaf(s, s, sn); }
        float scale = (sn / (1.f + sn)) / sqrtf(sn);
#pragma unroll
        for (int o = 0; o < 16; ++o) vout[o] = sv[o] * inv * scale;

        if (it < 2) {
            float d0 = 0.f, d1 = 0.f, d2 = 0.f;
#pragma unroll
            for (int o = 0; o < 16; ++o) {
                d0 = fmaf(pr[0][o], vout[o], d0);
                d1 = fmaf(pr[1][o], vout[o], d1);
                d2 = fmaf(pr[2][o], vout[o], d2);
            }
            l0 += d0; l1 += d1; l2 += d2;
        }
    }
    if (tid < 16) vbuf[(b * 10 + c) * 16 + tid] = vout[tid];
}

// --------------------------------------------------------------------------
__global__ void mask_k(const float* __restrict__ vbuf, float* __restrict__ out,
                       float* __restrict__ masked) {
    int b = blockIdx.x * 256 + threadIdx.x;
    if (b >= 512) return;
    const float* vp = vbuf + b * 160;
    float cls[10]; int best = 0; float bv = -1.f;
#pragma unroll
    for (int cc = 0; cc < 10; ++cc) {
        float sn = 0.f;
#pragma unroll
        for (int o = 0; o < 16; ++o) { float v = vp[cc * 16 + o]; sn = fmaf(v, v, sn); }
        cls[cc] = sqrtf(sn);
        if (cls[cc] > bv) { bv = cls[cc]; best = cc; }
    }
#pragma unroll
    for (int cc = 0; cc < 10; ++cc) {
        out[b * 10 + cc] = (cc == best) ? 1.f : 0.f;
        out[406528 + b * 10 + cc] = cls[cc];
    }
#pragma unroll
    for (int cc = 0; cc < 10; ++cc) {
        float keep = (cc == best) ? 1.f : 0.f;
#pragma unroll
        for (int o = 0; o < 16; ++o)
            masked[b * 160 + cc * 16 + o] = keep * vp[cc * 16 + o];
    }
}

// --------------------------------------------------------------------------
template <int ACT>
__global__ __launch_bounds__(256) void dec_gemm(const float* __restrict__ A,
                                                const float* __restrict__ Bw,
                                                const float* __restrict__ bias,
                                                float* __restrict__ C,
                                                int M, int N, int K) {
    __shared__ float As[16][68];
    __shared__ float Bs[16][68];
    int ntiles = (N + 63) >> 6;
    int mt = blockIdx.x / ntiles, nt = blockIdx.x - mt * ntiles;
    int m0 = mt * 64, n0 = nt * 64;
    int tid = threadIdx.x;
    int tx = tid & 15, ty = tid >> 4;
    int am = tid >> 2, ak = (tid & 3) * 4;
    int bk = tid >> 4, bn = (tid & 15) * 4;
    float acc[4][4];
#pragma unroll
    for (int i = 0; i < 4; ++i)
#pragma unroll
        for (int j = 0; j < 4; ++j) acc[i][j] = 0.f;

    for (int k0 = 0; k0 < K; k0 += 16) {
        float4 av = *(const float4*)(A + (m0 + am) * K + k0 + ak);
        float4 bv = make_float4(0.f, 0.f, 0.f, 0.f);
        if (n0 + bn < N) bv = *(const float4*)(Bw + (k0 + bk) * N + n0 + bn);
        __syncthreads();
        As[ak + 0][am] = av.x;
        As[ak + 1][am] = av.y;
        As[ak + 2][am] = av.z;
        As[ak + 3][am] = av.w;
        *(float4*)&Bs[bk][bn] = bv;
        __syncthreads();
#pragma unroll
        for (int kk = 0; kk < 16; ++kk) {
            float4 a = *(const float4*)&As[kk][ty * 4];
            float4 bb = *(const float4*)&Bs[kk][tx * 4];
            float aa[4] = {a.x, a.y, a.z, a.w};
            float bbb[4] = {bb.x, bb.y, bb.z, bb.w};
#pragma unroll
            for (int i = 0; i < 4; ++i)
#pragma unroll
                for (int j = 0; j < 4; ++j)
                    acc[i][j] = fmaf(aa[i], bbb[j], acc[i][j]);
        }
    }
#pragma unroll
    for (int i = 0; i < 4; ++i) {
        int m = m0 + ty * 4 + i;
#pragma unroll
        for (int j = 0; j < 4; ++j) {
            int n = n0 + tx * 4 + j;
            if (n < N) {
                float v = acc[i][j] + bias[n];
                if (ACT == 0) v = fmaxf(v, 0.f);
                else          v = 1.f / (1.f + expf(-v));
                C[m * N + n] = v;
            }
        }
    }
}

// --------------------------------------------------------------------------
extern "C" void kernel_launch(void* const* d_in, const int* in_sizes, int n_in,
                              void* d_out, int out_size, void* d_ws, size_t ws_size,
                              hipStream_t stream) {
    const float* x   = (const float*)d_in[0];
    const float* w1  = (const float*)d_in[1];
    const float* b1  = (const float*)d_in[2];
    const float* pw  = (const float*)d_in[3];
    const float* pb  = (const float*)d_in[4];
    const float* rw  = (const float*)d_in[5];
    const float* dw1 = (const float*)d_in[6];
    const float* db1 = (const float*)d_in[7];
    const float* dw2 = (const float*)d_in[8];
    const float* db2 = (const float*)d_in[9];
    const float* dw3 = (const float*)d_in[10];
    const float* db3 = (const float*)d_in[11];
    float* out = (float*)d_out;
    char* wsb  = (char*)d_ws;
    if (ws_size < (size_t)WS_BYTES) return;

    h16*   hhi  = (h16*)(wsb + OFFB_HHI);
    h16*   hlo  = (h16*)(wsb + OFFB_HLO);
    h16*   wthi = (h16*)(wsb + OFFB_WTHI);
    h16*   wtlo = (h16*)(wsb + OFFB_WTLO);
    float* wt1  = (float*)(wsb + OFFB_WT1);
    float* Cbuf = (float*)(wsb + OFFB_C);
    float* u    = (float*)(wsb + OFFB_U);
    float* vbuf = (float*)(wsb + OFFB_V);
    float* msk  = (float*)(wsb + OFFB_MSK);
    float* d1   = (float*)(wsb + OFFB_D1);
    float* d2   = (float*)(wsb + OFFB_D2);

    transpose_w1<<<81, 256, 0, stream>>>(w1, wt1);
    split_pw<<<20736, 256, 0, stream>>>(pw, wthi, wtlo);
    conv1_k<<<512, 448, 0, stream>>>(x, wt1, b1, hhi, hlo);
    prim_gemm_mfma<<<576, 256, 0, stream>>>(hhi, hlo, wthi, wtlo, pb, Cbuf);
    squash_k<<<2304, 256, 0, stream>>>(Cbuf, u);       // h dead from here on
    routing_k<<<5120, 384, 0, stream>>>(u, rw, vbuf);
    mask_k<<<2, 256, 0, stream>>>(vbuf, out, msk);
    dec_gemm<0><<<64, 256, 0, stream>>>(msk, dw1, db1, d1, 512, 512, 160);
    dec_gemm<0><<<128, 256, 0, stream>>>(d1, dw2, db2, d2, 512, 1024, 512);
    dec_gemm<1><<<104, 256, 0, stream>>>(d2, dw3, db3, out + 5120, 512, 784, 1024);
}

// Round 4
// 2385.639 us; speedup vs baseline: 2.0255x; 1.0679x over previous
//
#include <hip/hip_runtime.h>
#include <math.h>

// ---------------------------------------------------------------------------
// CapsuleNet forward (round 4): prim conv MFMA + split-K(4) + XCD swizzle.
// C = Ah*Bh + Ah*Bl + Al*Bh  (fp16 hi/lo split, ~2^-22 relative error).
// Partial K-sums atomically accumulated into C (pre-filled with bias).
// squash_k remapped for coalesced C reads.
// ---------------------------------------------------------------------------

typedef _Float16 h16;
typedef h16 frag8 __attribute__((ext_vector_type(8)));    // 8 halves = 16 B
typedef float f32x4 __attribute__((ext_vector_type(4)));

// workspace layout (BYTE offsets). Peak = 249,906,176 B.
#define OFFB_HHI   0L             // 52428800 halves = 104857600 B
#define OFFB_HLO   104857600L     // 52428800 halves
#define OFFB_WTHI  209715200L     // 5308416 halves = 10616832 B
#define OFFB_WTLO  220332032L     // 5308416 halves
#define OFFB_WT1   230948864L     // 20736 floats = 82944 B
#define OFFB_C     231031808L     // 4718592 floats -> end 249906176
#define WS_BYTES   249906176L
// aliased into dead h region after prim_gemm:
#define OFFB_U     0L             // 4718592 floats
#define OFFB_V     18874368L      // 81920 floats
#define OFFB_MSK   19202048L      // 81920 floats
#define OFFB_D1    19529728L      // 262144 floats
#define OFFB_D2    20578304L      // 524288 floats

// --------------------------------------------------------------------------
__global__ void transpose_w1(const float* __restrict__ w, float* __restrict__ wt) {
    int i = blockIdx.x * 256 + threadIdx.x;          // 20736 exact
    int k = i >> 8, oc = i & 255;
    wt[i] = w[oc * 81 + k];
}

// prim weights -> B^T fp16 hi/lo: wt[oc][k], k = tap*256+ic
__global__ void split_pw(const float* __restrict__ w,
                         h16* __restrict__ whi, h16* __restrict__ wlo) {
    int i = blockIdx.x * 256 + threadIdx.x;          // 5308416 exact
    int oc = i / 20736; int r = i - oc * 20736;
    int tap = r >> 8; int ic = r & 255;
    float v = w[(oc * 256 + ic) * 81 + tap];
    h16 hi = (h16)v;
    whi[i] = hi;
    wlo[i] = (h16)(v - (float)hi);
}

// C pre-fill with bias (also serves as the split-K zero-init)
__global__ void init_C(const float* __restrict__ bias, float* __restrict__ C) {
    int i = blockIdx.x * 256 + threadIdx.x;          // 4718592 exact
    C[i] = bias[i & 255];
}

// --------------------------------------------------------------------------
// conv1: x[b][28][28] * w -> h fp16 hi/lo, NHWC [b][y][x][oc], ReLU
__global__ __launch_bounds__(448) void conv1_k(const float* __restrict__ x,
                                               const float* __restrict__ wt1,
                                               const float* __restrict__ bias,
                                               h16* __restrict__ hhi,
                                               h16* __restrict__ hlo) {
    __shared__ float xs[784];
    int b = blockIdx.x;
    int tid = threadIdx.x;
    for (int i = tid; i < 784; i += 448) xs[i] = x[b * 784 + i];
    __syncthreads();
    if (tid >= 400) return;
    int oy = tid / 20, ox = tid - oy * 20;
    int xbase = oy * 28 + ox;
    long hb = ((long)(b * 20 + oy) * 20 + ox) * 256;
    for (int ocg = 0; ocg < 16; ++ocg) {
        int oc0 = ocg * 16;
        float acc[16];
#pragma unroll
        for (int j = 0; j < 16; ++j) acc[j] = bias[oc0 + j];
#pragma unroll
        for (int ky = 0; ky < 9; ++ky) {
#pragma unroll
            for (int kx = 0; kx < 9; ++kx) {
                float xv = xs[xbase + ky * 28 + kx];
                const float* wr = wt1 + (ky * 9 + kx) * 256 + oc0;
#pragma unroll
                for (int j = 0; j < 16; ++j) acc[j] = fmaf(wr[j], xv, acc[j]);
            }
        }
        frag8 h0, h1, l0, l1;
#pragma unroll
        for (int j = 0; j < 8; ++j) {
            float v0 = fmaxf(acc[j], 0.f);
            float v1 = fmaxf(acc[j + 8], 0.f);
            h16 a = (h16)v0, bb = (h16)v1;
            h0[j] = a; l0[j] = (h16)(v0 - (float)a);
            h1[j] = bb; l1[j] = (h16)(v1 - (float)bb);
        }
        *(frag8*)(hhi + hb + oc0)     = h0;
        *(frag8*)(hhi + hb + oc0 + 8) = h1;
        *(frag8*)(hlo + hb + oc0)     = l0;
        *(frag8*)(hlo + hb + oc0 + 8) = l1;
    }
}

// --------------------------------------------------------------------------
// prim conv MFMA GEMM, split-K x4 with atomic accumulate.
// Grid 2304: blockIdx -> (mt, nt, kt) with (nt,kt) a function of bx%16 so
// same-XCD blocks (bx%8) stream the same 64-col B stripe (L2 locality).
#define LDK 40   // padded LDS k-stride (halves)
__global__ __launch_bounds__(256, 2) void prim_gemm_mfma(
        const h16* __restrict__ Ahi, const h16* __restrict__ Alo,
        const h16* __restrict__ Bhi, const h16* __restrict__ Blo,
        float* __restrict__ C) {
    __shared__ h16 As[2][128][LDK];
    __shared__ h16 Bs[2][64][LDK];
    int tid = threadIdx.x;
    int bx = blockIdx.x;                  // 2304 blocks
    int r16 = bx & 15;
    int combo = ((r16 & 7) << 1) | (r16 >> 3);   // 0..15, bijective in r16
    int nt = combo >> 2, kt = combo & 3;
    int mt = bx >> 4;                     // 0..143
    int n0 = nt * 64;
    int kb0 = kt * 162;                   // 162 k-steps of 32 halves each

    int wave = tid >> 6;
    int wm = wave >> 1, wn = wave & 1;    // wave tile origin: (wm*64, wn*32)
    int lane = tid & 63;
    int lm = lane & 15, quad = lane >> 4;

    // A staging: thread -> row ra = tid>>1, 16-half segment sa = (tid&1)*16
    int ra = tid >> 1;
    int sa = (tid & 1) * 16;
    int ma = mt * 128 + ra;
    int b = ma / 36, pos = ma - b * 36;
    int oy = pos / 6, ox = pos - oy * 6;
    long abase = ((long)(b * 20 + 2 * oy) * 20 + 2 * ox) * 256 + sa;
    // B staging: row rb = tid>>2, 8-half segment sb = (tid&3)*8
    int rb = tid >> 2;
    int sb = (tid & 3) * 8;
    long bbase = (long)(n0 + rb) * 20736 + sb;

    float4 pa0h, pa1h, pa0l, pa1l, pbh, pbl;
    auto gload = [&](int kb) {
        int tap = kb >> 3;
        int ic0 = (kb & 7) << 5;
        int ky = tap / 9, kx = tap - ky * 9;
        long aoff = abase + (ky * 20 + kx) * 256 + ic0;
        pa0h = *(const float4*)(Ahi + aoff);
        pa1h = *(const float4*)(Ahi + aoff + 8);
        pa0l = *(const float4*)(Alo + aoff);
        pa1l = *(const float4*)(Alo + aoff + 8);
        long boff = bbase + (long)kb * 32;
        pbh = *(const float4*)(Bhi + boff);
        pbl = *(const float4*)(Blo + boff);
    };

    f32x4 acc[4][2];
#pragma unroll
    for (int i = 0; i < 4; ++i)
#pragma unroll
        for (int j = 0; j < 2; ++j) acc[i][j] = (f32x4){0.f, 0.f, 0.f, 0.f};

    gload(kb0);
    for (int it = 0; it < 162; ++it) {
        __syncthreads();
        *(float4*)&As[0][ra][sa]     = pa0h;
        *(float4*)&As[0][ra][sa + 8] = pa1h;
        *(float4*)&As[1][ra][sa]     = pa0l;
        *(float4*)&As[1][ra][sa + 8] = pa1l;
        *(float4*)&Bs[0][rb][sb]     = pbh;
        *(float4*)&Bs[1][rb][sb]     = pbl;
        __syncthreads();
        if (it + 1 < 162) gload(kb0 + it + 1);

        frag8 ah[4], al[4], bh[2], bl[2];
#pragma unroll
        for (int mi = 0; mi < 4; ++mi) {
            int row = wm * 64 + mi * 16 + lm;
            ah[mi] = *(const frag8*)&As[0][row][quad * 8];
            al[mi] = *(const frag8*)&As[1][row][quad * 8];
        }
#pragma unroll
        for (int ni = 0; ni < 2; ++ni) {
            int col = wn * 32 + ni * 16 + lm;
            bh[ni] = *(const frag8*)&Bs[0][col][quad * 8];
            bl[ni] = *(const frag8*)&Bs[1][col][quad * 8];
        }
#pragma unroll
        for (int mi = 0; mi < 4; ++mi)
#pragma unroll
            for (int ni = 0; ni < 2; ++ni) {
                acc[mi][ni] = __builtin_amdgcn_mfma_f32_16x16x32_f16(
                    ah[mi], bh[ni], acc[mi][ni], 0, 0, 0);
                acc[mi][ni] = __builtin_amdgcn_mfma_f32_16x16x32_f16(
                    ah[mi], bl[ni], acc[mi][ni], 0, 0, 0);
                acc[mi][ni] = __builtin_amdgcn_mfma_f32_16x16x32_f16(
                    al[mi], bh[ni], acc[mi][ni], 0, 0, 0);
            }
    }

    // epilogue: C/D layout col = lane&15, row = quad*4 + reg; atomic split-K
#pragma unroll
    for (int ni = 0; ni < 2; ++ni) {
        int n = n0 + wn * 32 + ni * 16 + lm;
#pragma unroll
        for (int mi = 0; mi < 4; ++mi) {
            int m = mt * 128 + wm * 64 + mi * 16 + quad * 4;
#pragma unroll
            for (int r = 0; r < 4; ++r)
                atomicAdd(&C[(long)(m + r) * 256 + n], acc[mi][ni][r]);
        }
    }
}

// --------------------------------------------------------------------------
// squash: C[(b*36+pos)][256] -> u[b][n=ci*36+pos][i], coalesced C reads.
__global__ void squash_k(const float* __restrict__ C, float* __restrict__ u) {
    int t = blockIdx.x * 256 + threadIdx.x;          // 589824 exact
    int row = t >> 5;                                 // (b*36+pos)
    int ci = t & 31;
    int b = row / 36, pos = row - b * 36;
    const float* src = C + (long)row * 256 + ci;
    float v[8]; float sn = 0.f;
#pragma unroll
    for (int i = 0; i < 8; ++i) { v[i] = src[i * 32]; sn = fmaf(v[i], v[i], sn); }
    float scale = (sn / (1.f + sn)) / sqrtf(sn);
    float* dst = u + ((long)b * 1152 + ci * 36 + pos) * 8;
    float4 o0 = make_float4(v[0]*scale, v[1]*scale, v[2]*scale, v[3]*scale);
    float4 o1 = make_float4(v[4]*scale, v[5]*scale, v[6]*scale, v[7]*scale);
    *(float4*)(dst) = o0;
    *(float4*)(dst + 4) = o1;
}

// --------------------------------------------------------------------------
// routing: one block per (c,b). 384 threads; each owns 3 route nodes.
__global__ __launch_bounds__(384) void routing_k(const float* __restrict__ u,
                                                 const float* __restrict__ rw,
                                                 float* __restrict__ vbuf) {
    int c = blockIdx.x >> 9;
    int b = blockIdx.x & 511;
    int tid = threadIdx.x;
    int wid = tid >> 6;
    int lane = tid & 63;
    __shared__ float wred[6][20];

    float pr[3][16];
#pragma unroll
    for (int r = 0; r < 3; ++r) {
        int n = tid + r * 384;
        const float4* up = (const float4*)(u + (b * 1152 + n) * 8);
        float4 ua = up[0], ub = up[1];
        float uu[8] = {ua.x, ua.y, ua.z, ua.w, ub.x, ub.y, ub.z, ub.w};
        const float4* wp = (const float4*)(rw + ((long)c * 1152 + n) * 128);
#pragma unroll
        for (int o = 0; o < 16; ++o) pr[r][o] = 0.f;
#pragma unroll
        for (int i = 0; i < 8; ++i) {
#pragma unroll
            for (int o4 = 0; o4 < 4; ++o4) {
                float4 w4 = wp[i * 4 + o4];
                pr[r][o4*4+0] = fmaf(uu[i], w4.x, pr[r][o4*4+0]);
                pr[r][o4*4+1] = fmaf(uu[i], w4.y, pr[r][o4*4+1]);
                pr[r][o4*4+2] = fmaf(uu[i], w4.z, pr[r][o4*4+2]);
                pr[r][o4*4+3] = fmaf(uu[i], w4.w, pr[r][o4*4+3]);
            }
        }
    }

    float l0 = 0.f, l1 = 0.f, l2 = 0.f;
    float vout[16];
    for (int it = 0; it < 3; ++it) {
        float lm = fmaxf(fmaxf(l0, l1), l2);
#pragma unroll
        for (int m = 32; m >= 1; m >>= 1) lm = fmaxf(lm, __shfl_xor(lm, m));
        if (lane == 0) wred[wid][17] = lm;
        __syncthreads();
        float maxv = wred[0][17];
#pragma unroll
        for (int w = 1; w < 6; ++w) maxv = fmaxf(maxv, wred[w][17]);

        float e0 = expf(l0 - maxv), e1 = expf(l1 - maxv), e2 = expf(l2 - maxv);
        float red[17];
#pragma unroll
        for (int o = 0; o < 16; ++o)
            red[o] = fmaf(e0, pr[0][o], fmaf(e1, pr[1][o], e2 * pr[2][o]));
        red[16] = e0 + e1 + e2;
#pragma unroll
        for (int o = 0; o < 17; ++o) {
#pragma unroll
            for (int m = 32; m >= 1; m >>= 1) red[o] += __shfl_xor(red[o], m);
        }
        __syncthreads();
        if (lane == 0) {
#pragma unroll
            for (int o = 0; o < 17; ++o) wred[wid][o] = red[o];
        }
        __syncthreads();
        float sv[17];
#pragma unroll
        for (int o = 0; o < 17; ++o) {
            float tacc = wred[0][o];
#pragma unroll
            for (int w = 1; w < 6; ++w) tacc += wred[w][o];
            sv[o] = tacc;
        }
        float inv = 1.f / sv[16];
        float sn = 0.f;
#pragma unroll
        for (int o = 0; o < 16; ++o) { float s = sv[o] * inv; sn = fmaf(s, s, sn); }
        float scale = (sn / (1.f + sn)) / sqrtf(sn);
#pragma unroll
        for (int o = 0; o < 16; ++o) vout[o] = sv[o] * inv * scale;

        if (it < 2) {
            float d0 = 0.f, d1 = 0.f, d2 = 0.f;
#pragma unroll
            for (int o = 0; o < 16; ++o) {
                d0 = fmaf(pr[0][o], vout[o], d0);
                d1 = fmaf(pr[1][o], vout[o], d1);
                d2 = fmaf(pr[2][o], vout[o], d2);
            }
            l0 += d0; l1 += d1; l2 += d2;
        }
    }
    if (tid < 16) vbuf[(b * 10 + c) * 16 + tid] = vout[tid];
}

// --------------------------------------------------------------------------
__global__ void mask_k(const float* __restrict__ vbuf, float* __restrict__ out,
                       float* __restrict__ masked) {
    int b = blockIdx.x * 256 + threadIdx.x;
    if (b >= 512) return;
    const float* vp = vbuf + b * 160;
    float cls[10]; int best = 0; float bv = -1.f;
#pragma unroll
    for (int cc = 0; cc < 10; ++cc) {
        float sn = 0.f;
#pragma unroll
        for (int o = 0; o < 16; ++o) { float v = vp[cc * 16 + o]; sn = fmaf(v, v, sn); }
        cls[cc] = sqrtf(sn);
        if (cls[cc] > bv) { bv = cls[cc]; best = cc; }
    }
#pragma unroll
    for (int cc = 0; cc < 10; ++cc) {
        out[b * 10 + cc] = (cc == best) ? 1.f : 0.f;
        out[406528 + b * 10 + cc] = cls[cc];
    }
#pragma unroll
    for (int cc = 0; cc < 10; ++cc) {
        float keep = (cc == best) ? 1.f : 0.f;
#pragma unroll
        for (int o = 0; o < 16; ++o)
            masked[b * 160 + cc * 16 + o] = keep * vp[cc * 16 + o];
    }
}

// --------------------------------------------------------------------------
template <int ACT>
__global__ __launch_bounds__(256) void dec_gemm(const float* __restrict__ A,
                                                const float* __restrict__ Bw,
                                                const float* __restrict__ bias,
                                                float* __restrict__ C,
                                                int M, int N, int K) {
    __shared__ float As[16][68];
    __shared__ float Bs[16][68];
    int ntiles = (N + 63) >> 6;
    int mt = blockIdx.x / ntiles, nt = blockIdx.x - mt * ntiles;
    int m0 = mt * 64, n0 = nt * 64;
    int tid = threadIdx.x;
    int tx = tid & 15, ty = tid >> 4;
    int am = tid >> 2, ak = (tid & 3) * 4;
    int bk = tid >> 4, bn = (tid & 15) * 4;
    float acc[4][4];
#pragma unroll
    for (int i = 0; i < 4; ++i)
#pragma unroll
        for (int j = 0; j < 4; ++j) acc[i][j] = 0.f;

    for (int k0 = 0; k0 < K; k0 += 16) {
        float4 av = *(const float4*)(A + (m0 + am) * K + k0 + ak);
        float4 bv = make_float4(0.f, 0.f, 0.f, 0.f);
        if (n0 + bn < N) bv = *(const float4*)(Bw + (k0 + bk) * N + n0 + bn);
        __syncthreads();
        As[ak + 0][am] = av.x;
        As[ak + 1][am] = av.y;
        As[ak + 2][am] = av.z;
        As[ak + 3][am] = av.w;
        *(float4*)&Bs[bk][bn] = bv;
        __syncthreads();
#pragma unroll
        for (int kk = 0; kk < 16; ++kk) {
            float4 a = *(const float4*)&As[kk][ty * 4];
            float4 bb = *(const float4*)&Bs[kk][tx * 4];
            float aa[4] = {a.x, a.y, a.z, a.w};
            float bbb[4] = {bb.x, bb.y, bb.z, bb.w};
#pragma unroll
            for (int i = 0; i < 4; ++i)
#pragma unroll
                for (int j = 0; j < 4; ++j)
                    acc[i][j] = fmaf(aa[i], bbb[j], acc[i][j]);
        }
    }
#pragma unroll
    for (int i = 0; i < 4; ++i) {
        int m = m0 + ty * 4 + i;
#pragma unroll
        for (int j = 0; j < 4; ++j) {
            int n = n0 + tx * 4 + j;
            if (n < N) {
                float v = acc[i][j] + bias[n];
                if (ACT == 0) v = fmaxf(v, 0.f);
                else          v = 1.f / (1.f + expf(-v));
                C[m * N + n] = v;
            }
        }
    }
}

// --------------------------------------------------------------------------
extern "C" void kernel_launch(void* const* d_in, const int* in_sizes, int n_in,
                              void* d_out, int out_size, void* d_ws, size_t ws_size,
                              hipStream_t stream) {
    const float* x   = (const float*)d_in[0];
    const float* w1  = (const float*)d_in[1];
    const float* b1  = (const float*)d_in[2];
    const float* pw  = (const float*)d_in[3];
    const float* pb  = (const float*)d_in[4];
    const float* rw  = (const float*)d_in[5];
    const float* dw1 = (const float*)d_in[6];
    const float* db1 = (const float*)d_in[7];
    const float* dw2 = (const float*)d_in[8];
    const float* db2 = (const float*)d_in[9];
    const float* dw3 = (const float*)d_in[10];
    const float* db3 = (const float*)d_in[11];
    float* out = (float*)d_out;
    char* wsb  = (char*)d_ws;
    if (ws_size < (size_t)WS_BYTES) return;

    h16*   hhi  = (h16*)(wsb + OFFB_HHI);
    h16*   hlo  = (h16*)(wsb + OFFB_HLO);
    h16*   wthi = (h16*)(wsb + OFFB_WTHI);
    h16*   wtlo = (h16*)(wsb + OFFB_WTLO);
    float* wt1  = (float*)(wsb + OFFB_WT1);
    float* Cbuf = (float*)(wsb + OFFB_C);
    float* u    = (float*)(wsb + OFFB_U);
    float* vbuf = (float*)(wsb + OFFB_V);
    float* msk  = (float*)(wsb + OFFB_MSK);
    float* d1   = (float*)(wsb + OFFB_D1);
    float* d2   = (float*)(wsb + OFFB_D2);

    transpose_w1<<<81, 256, 0, stream>>>(w1, wt1);
    split_pw<<<20736, 256, 0, stream>>>(pw, wthi, wtlo);
    conv1_k<<<512, 448, 0, stream>>>(x, wt1, b1, hhi, hlo);
    init_C<<<18432, 256, 0, stream>>>(pb, Cbuf);
    prim_gemm_mfma<<<2304, 256, 0, stream>>>(hhi, hlo, wthi, wtlo, Cbuf);
    squash_k<<<2304, 256, 0, stream>>>(Cbuf, u);       // h dead from here on
    routing_k<<<5120, 384, 0, stream>>>(u, rw, vbuf);
    mask_k<<<2, 256, 0, stream>>>(vbuf, out, msk);
    dec_gemm<0><<<64, 256, 0, stream>>>(msk, dw1, db1, d1, 512, 512, 160);
    dec_gemm<0><<<128, 256, 0, stream>>>(d1, dw2, db2, d2, 512, 1024, 512);
    dec_gemm<1><<<104, 256, 0, stream>>>(d2, dw3, db3, out + 5120, 512, 784, 1024);
}

// Round 5
// 1891.500 us; speedup vs baseline: 2.5546x; 1.2612x over previous
//
#include <hip/hip_runtime.h>
#include <math.h>

// ---------------------------------------------------------------------------
// CapsuleNet forward (round 5): prim MFMA GEMM, BM=128 BN=128 splitK8,
// kt pinned to XCD (kt = bx&7) so each XCD's 2.65 MB B-slice stays L2-hot.
// C = Ah*Bh + Ah*Bl + Al*Bh  (fp16 hi/lo split, ~2^-22 relative error).
// split_pw rewritten with LDS transpose (coalesced reads).
// ---------------------------------------------------------------------------

typedef _Float16 h16;
typedef h16 frag8 __attribute__((ext_vector_type(8)));    // 8 halves = 16 B
typedef float f32x4 __attribute__((ext_vector_type(4)));

// workspace layout (BYTE offsets). Peak = 249,906,176 B.
#define OFFB_HHI   0L             // 52428800 halves = 104857600 B
#define OFFB_HLO   104857600L     // 52428800 halves
#define OFFB_WTHI  209715200L     // 5308416 halves = 10616832 B
#define OFFB_WTLO  220332032L     // 5308416 halves
#define OFFB_WT1   230948864L     // 20736 floats = 82944 B
#define OFFB_C     231031808L     // 4718592 floats -> end 249906176
#define WS_BYTES   249906176L
// aliased into dead h region after prim_gemm:
#define OFFB_U     0L             // 4718592 floats
#define OFFB_V     18874368L      // 81920 floats
#define OFFB_MSK   19202048L      // 81920 floats
#define OFFB_D1    19529728L      // 262144 floats
#define OFFB_D2    20578304L      // 524288 floats

// --------------------------------------------------------------------------
__global__ void transpose_w1(const float* __restrict__ w, float* __restrict__ wt) {
    int i = blockIdx.x * 256 + threadIdx.x;          // 20736 exact
    int k = i >> 8, oc = i & 255;
    wt[i] = w[oc * 81 + k];
}

// prim weights -> B^T fp16 hi/lo: wt[oc][k], k = tap*256+ic.
// One block per oc; 8 chunks of 32 ic; LDS transpose, coalesced global reads.
__global__ __launch_bounds__(256) void split_pw(const float* __restrict__ w,
                                                h16* __restrict__ whi,
                                                h16* __restrict__ wlo) {
    __shared__ float s[2592];                        // 32 ic x 81 taps
    int oc = blockIdx.x;
    int tid = threadIdx.x;
    long src0 = (long)oc * 20736;
    long dst0 = (long)oc * 20736;
    for (int ch = 0; ch < 8; ++ch) {
        int ic0 = ch * 32;
        __syncthreads();
        for (int e = tid; e < 2592; e += 256) s[e] = w[src0 + ic0 * 81 + e];
        __syncthreads();
        for (int e = tid; e < 2592; e += 256) {
            int tap = e >> 5, icf = e & 31;          // banks: icf*81%32 distinct
            float v = s[icf * 81 + tap];
            h16 hi = (h16)v;
            long d = dst0 + tap * 256 + ic0 + icf;
            whi[d] = hi;
            wlo[d] = (h16)(v - (float)hi);
        }
    }
}

// C pre-fill with bias (also the split-K zero-init)
__global__ void init_C(const float* __restrict__ bias, float* __restrict__ C) {
    int i = blockIdx.x * 256 + threadIdx.x;          // 4718592 exact
    C[i] = bias[i & 255];
}

// --------------------------------------------------------------------------
// conv1: x[b][28][28] * w -> h fp16 hi/lo, NHWC [b][y][x][oc], ReLU
__global__ __launch_bounds__(448) void conv1_k(const float* __restrict__ x,
                                               const float* __restrict__ wt1,
                                               const float* __restrict__ bias,
                                               h16* __restrict__ hhi,
                                               h16* __restrict__ hlo) {
    __shared__ float xs[784];
    int b = blockIdx.x;
    int tid = threadIdx.x;
    for (int i = tid; i < 784; i += 448) xs[i] = x[b * 784 + i];
    __syncthreads();
    if (tid >= 400) return;
    int oy = tid / 20, ox = tid - oy * 20;
    int xbase = oy * 28 + ox;
    long hb = ((long)(b * 20 + oy) * 20 + ox) * 256;
    for (int ocg = 0; ocg < 16; ++ocg) {
        int oc0 = ocg * 16;
        float acc[16];
#pragma unroll
        for (int j = 0; j < 16; ++j) acc[j] = bias[oc0 + j];
#pragma unroll
        for (int ky = 0; ky < 9; ++ky) {
#pragma unroll
            for (int kx = 0; kx < 9; ++kx) {
                float xv = xs[xbase + ky * 28 + kx];
                const float* wr = wt1 + (ky * 9 + kx) * 256 + oc0;
#pragma unroll
                for (int j = 0; j < 16; ++j) acc[j] = fmaf(wr[j], xv, acc[j]);
            }
        }
        frag8 h0, h1, l0, l1;
#pragma unroll
        for (int j = 0; j < 8; ++j) {
            float v0 = fmaxf(acc[j], 0.f);
            float v1 = fmaxf(acc[j + 8], 0.f);
            h16 a = (h16)v0, bb = (h16)v1;
            h0[j] = a; l0[j] = (h16)(v0 - (float)a);
            h1[j] = bb; l1[j] = (h16)(v1 - (float)bb);
        }
        *(frag8*)(hhi + hb + oc0)     = h0;
        *(frag8*)(hhi + hb + oc0 + 8) = h1;
        *(frag8*)(hlo + hb + oc0)     = l0;
        *(frag8*)(hlo + hb + oc0 + 8) = l1;
    }
}

// --------------------------------------------------------------------------
// prim conv MFMA GEMM: BM=128 BN=128 BK=32, split-K x8, atomic accumulate.
// Grid 2304: kt = bx&7 (== XCD id under round-robin dispatch -> B-slice
// L2-resident), nt = (bx>>3)&1, mt = bx>>4.
#define LDK 40   // padded LDS k-stride (halves), 80 B rows (16 B-aligned)
__global__ __launch_bounds__(256, 2) void prim_gemm_mfma(
        const h16* __restrict__ Ahi, const h16* __restrict__ Alo,
        const h16* __restrict__ Bhi, const h16* __restrict__ Blo,
        float* __restrict__ C) {
    __shared__ h16 As[2][128][LDK];
    __shared__ h16 Bs[2][128][LDK];
    int tid = threadIdx.x;
    int bx = blockIdx.x;                  // 2304 blocks
    int kt = bx & 7;
    int nt = (bx >> 3) & 1;
    int mt = bx >> 4;                     // 0..143
    int n0 = nt * 128;
    int kb0 = kt * 81;                    // 81 k-steps of 32 halves each

    int wave = tid >> 6;
    int wm = wave >> 1, wn = wave & 1;    // wave tile origin: (wm*64, wn*64)
    int lane = tid & 63;
    int lm = lane & 15, quad = lane >> 4;

    // A staging: row ra = tid>>1, 16-half segment sa = (tid&1)*16
    int ra = tid >> 1;
    int sa = (tid & 1) * 16;
    int ma = mt * 128 + ra;
    int b = ma / 36, pos = ma - b * 36;
    int oy = pos / 6, ox = pos - oy * 6;
    long abase = ((long)(b * 20 + 2 * oy) * 20 + 2 * ox) * 256 + sa;
    // B staging: row rb = tid>>1, 16-half segment sb = (tid&1)*16
    long bbase = (long)(n0 + ra) * 20736 + sa;

    float4 pa0h, pa1h, pa0l, pa1l, pb0h, pb1h, pb0l, pb1l;
    auto gload = [&](int kb) {
        int tap = kb >> 3;
        int ic0 = (kb & 7) << 5;
        int ky = tap / 9, kx = tap - ky * 9;
        long aoff = abase + (ky * 20 + kx) * 256 + ic0;
        pa0h = *(const float4*)(Ahi + aoff);
        pa1h = *(const float4*)(Ahi + aoff + 8);
        pa0l = *(const float4*)(Alo + aoff);
        pa1l = *(const float4*)(Alo + aoff + 8);
        long boff = bbase + (long)kb * 32;
        pb0h = *(const float4*)(Bhi + boff);
        pb1h = *(const float4*)(Bhi + boff + 8);
        pb0l = *(const float4*)(Blo + boff);
        pb1l = *(const float4*)(Blo + boff + 8);
    };

    f32x4 acc[4][4];
#pragma unroll
    for (int i = 0; i < 4; ++i)
#pragma unroll
        for (int j = 0; j < 4; ++j) acc[i][j] = (f32x4){0.f, 0.f, 0.f, 0.f};

    gload(kb0);
    for (int it = 0; it < 81; ++it) {
        __syncthreads();
        *(float4*)&As[0][ra][sa]     = pa0h;
        *(float4*)&As[0][ra][sa + 8] = pa1h;
        *(float4*)&As[1][ra][sa]     = pa0l;
        *(float4*)&As[1][ra][sa + 8] = pa1l;
        *(float4*)&Bs[0][ra][sa]     = pb0h;
        *(float4*)&Bs[0][ra][sa + 8] = pb1h;
        *(float4*)&Bs[1][ra][sa]     = pb0l;
        *(float4*)&Bs[1][ra][sa + 8] = pb1l;
        __syncthreads();
        if (it + 1 < 81) gload(kb0 + it + 1);

        frag8 ah[4], al[4], bh[4], bl[4];
#pragma unroll
        for (int mi = 0; mi < 4; ++mi) {
            int row = wm * 64 + mi * 16 + lm;
            ah[mi] = *(const frag8*)&As[0][row][quad * 8];
            al[mi] = *(const frag8*)&As[1][row][quad * 8];
        }
#pragma unroll
        for (int ni = 0; ni < 4; ++ni) {
            int col = wn * 64 + ni * 16 + lm;
            bh[ni] = *(const frag8*)&Bs[0][col][quad * 8];
            bl[ni] = *(const frag8*)&Bs[1][col][quad * 8];
        }
#pragma unroll
        for (int mi = 0; mi < 4; ++mi)
#pragma unroll
            for (int ni = 0; ni < 4; ++ni) {
                acc[mi][ni] = __builtin_amdgcn_mfma_f32_16x16x32_f16(
                    ah[mi], bh[ni], acc[mi][ni], 0, 0, 0);
                acc[mi][ni] = __builtin_amdgcn_mfma_f32_16x16x32_f16(
                    ah[mi], bl[ni], acc[mi][ni], 0, 0, 0);
                acc[mi][ni] = __builtin_amdgcn_mfma_f32_16x16x32_f16(
                    al[mi], bh[ni], acc[mi][ni], 0, 0, 0);
            }
    }

    // epilogue: C/D layout col = lane&15, row = quad*4 + reg; atomic split-K
#pragma unroll
    for (int ni = 0; ni < 4; ++ni) {
        int n = n0 + wn * 64 + ni * 16 + lm;
#pragma unroll
        for (int mi = 0; mi < 4; ++mi) {
            int m = mt * 128 + wm * 64 + mi * 16 + quad * 4;
#pragma unroll
            for (int r = 0; r < 4; ++r)
                atomicAdd(&C[(long)(m + r) * 256 + n], acc[mi][ni][r]);
        }
    }
}

// --------------------------------------------------------------------------
// squash: C[(b*36+pos)][256] -> u[b][n=ci*36+pos][i], coalesced C reads.
__global__ void squash_k(const float* __restrict__ C, float* __restrict__ u) {
    int t = blockIdx.x * 256 + threadIdx.x;          // 589824 exact
    int row = t >> 5;                                 // (b*36+pos)
    int ci = t & 31;
    int b = row / 36, pos = row - b * 36;
    const float* src = C + (long)row * 256 + ci;
    float v[8]; float sn = 0.f;
#pragma unroll
    for (int i = 0; i < 8; ++i) { v[i] = src[i * 32]; sn = fmaf(v[i], v[i], sn); }
    float scale = (sn / (1.f + sn)) / sqrtf(sn);
    float* dst = u + ((long)b * 1152 + ci * 36 + pos) * 8;
    float4 o0 = make_float4(v[0]*scale, v[1]*scale, v[2]*scale, v[3]*scale);
    float4 o1 = make_float4(v[4]*scale, v[5]*scale, v[6]*scale, v[7]*scale);
    *(float4*)(dst) = o0;
    *(float4*)(dst + 4) = o1;
}

// --------------------------------------------------------------------------
// routing: one block per (c,b). 384 threads; each owns 3 route nodes.
__global__ __launch_bounds__(384) void routing_k(const float* __restrict__ u,
                                                 const float* __restrict__ rw,
                                                 float* __restrict__ vbuf) {
    int c = blockIdx.x >> 9;
    int b = blockIdx.x & 511;
    int tid = threadIdx.x;
    int wid = tid >> 6;
    int lane = tid & 63;
    __shared__ float wred[6][20];

    float pr[3][16];
#pragma unroll
    for (int r = 0; r < 3; ++r) {
        int n = tid + r * 384;
        const float4* up = (const float4*)(u + (b * 1152 + n) * 8);
        float4 ua = up[0], ub = up[1];
        float uu[8] = {ua.x, ua.y, ua.z, ua.w, ub.x, ub.y, ub.z, ub.w};
        const float4* wp = (const float4*)(rw + ((long)c * 1152 + n) * 128);
#pragma unroll
        for (int o = 0; o < 16; ++o) pr[r][o] = 0.f;
#pragma unroll
        for (int i = 0; i < 8; ++i) {
#pragma unroll
            for (int o4 = 0; o4 < 4; ++o4) {
                float4 w4 = wp[i * 4 + o4];
                pr[r][o4*4+0] = fmaf(uu[i], w4.x, pr[r][o4*4+0]);
                pr[r][o4*4+1] = fmaf(uu[i], w4.y, pr[r][o4*4+1]);
                pr[r][o4*4+2] = fmaf(uu[i], w4.z, pr[r][o4*4+2]);
                pr[r][o4*4+3] = fmaf(uu[i], w4.w, pr[r][o4*4+3]);
            }
        }
    }

    float l0 = 0.f, l1 = 0.f, l2 = 0.f;
    float vout[16];
    for (int it = 0; it < 3; ++it) {
        float lm = fmaxf(fmaxf(l0, l1), l2);
#pragma unroll
        for (int m = 32; m >= 1; m >>= 1) lm = fmaxf(lm, __shfl_xor(lm, m));
        if (lane == 0) wred[wid][17] = lm;
        __syncthreads();
        float maxv = wred[0][17];
#pragma unroll
        for (int w = 1; w < 6; ++w) maxv = fmaxf(maxv, wred[w][17]);

        float e0 = expf(l0 - maxv), e1 = expf(l1 - maxv), e2 = expf(l2 - maxv);
        float red[17];
#pragma unroll
        for (int o = 0; o < 16; ++o)
            red[o] = fmaf(e0, pr[0][o], fmaf(e1, pr[1][o], e2 * pr[2][o]));
        red[16] = e0 + e1 + e2;
#pragma unroll
        for (int o = 0; o < 17; ++o) {
#pragma unroll
            for (int m = 32; m >= 1; m >>= 1) red[o] += __shfl_xor(red[o], m);
        }
        __syncthreads();
        if (lane == 0) {
#pragma unroll
            for (int o = 0; o < 17; ++o) wred[wid][o] = red[o];
        }
        __syncthreads();
        float sv[17];
#pragma unroll
        for (int o = 0; o < 17; ++o) {
            float tacc = wred[0][o];
#pragma unroll
            for (int w = 1; w < 6; ++w) tacc += wred[w][o];
            sv[o] = tacc;
        }
        float inv = 1.f / sv[16];
        float sn = 0.f;
#pragma unroll
        for (int o = 0; o < 16; ++o) { float s = sv[o] * inv; sn = fmaf(s, s, sn); }
        float scale = (sn / (1.f + sn)) / sqrtf(sn);
#pragma unroll
        for (int o = 0; o < 16; ++o) vout[o] = sv[o] * inv * scale;

        if (it < 2) {
            float d0 = 0.f, d1 = 0.f, d2 = 0.f;
#pragma unroll
            for (int o = 0; o < 16; ++o) {
                d0 = fmaf(pr[0][o], vout[o], d0);
                d1 = fmaf(pr[1][o], vout[o], d1);
                d2 = fmaf(pr[2][o], vout[o], d2);
            }
            l0 += d0; l1 += d1; l2 += d2;
        }
    }
    if (tid < 16) vbuf[(b * 10 + c) * 16 + tid] = vout[tid];
}

// --------------------------------------------------------------------------
__global__ void mask_k(const float* __restrict__ vbuf, float* __restrict__ out,
                       float* __restrict__ masked) {
    int b = blockIdx.x * 256 + threadIdx.x;
    if (b >= 512) return;
    const float* vp = vbuf + b * 160;
    float cls[10]; int best = 0; float bv = -1.f;
#pragma unroll
    for (int cc = 0; cc < 10; ++cc) {
        float sn = 0.f;
#pragma unroll
        for (int o = 0; o < 16; ++o) { float v = vp[cc * 16 + o]; sn = fmaf(v, v, sn); }
        cls[cc] = sqrtf(sn);
        if (cls[cc] > bv) { bv = cls[cc]; best = cc; }
    }
#pragma unroll
    for (int cc = 0; cc < 10; ++cc) {
        out[b * 10 + cc] = (cc == best) ? 1.f : 0.f;
        out[406528 + b * 10 + cc] = cls[cc];
    }
#pragma unroll
    for (int cc = 0; cc < 10; ++cc) {
        float keep = (cc == best) ? 1.f : 0.f;
#pragma unroll
        for (int o = 0; o < 16; ++o)
            masked[b * 160 + cc * 16 + o] = keep * vp[cc * 16 + o];
    }
}

// --------------------------------------------------------------------------
template <int ACT>
__global__ __launch_bounds__(256) void dec_gemm(const float* __restrict__ A,
                                                const float* __restrict__ Bw,
                                                const float* __restrict__ bias,
                                                float* __restrict__ C,
                                                int M, int N, int K) {
    __shared__ float As[16][68];
    __shared__ float Bs[16][68];
    int ntiles = (N + 63) >> 6;
    int mt = blockIdx.x / ntiles, nt = blockIdx.x - mt * ntiles;
    int m0 = mt * 64, n0 = nt * 64;
    int tid = threadIdx.x;
    int tx = tid & 15, ty = tid >> 4;
    int am = tid >> 2, ak = (tid & 3) * 4;
    int bk = tid >> 4, bn = (tid & 15) * 4;
    float acc[4][4];
#pragma unroll
    for (int i = 0; i < 4; ++i)
#pragma unroll
        for (int j = 0; j < 4; ++j) acc[i][j] = 0.f;

    for (int k0 = 0; k0 < K; k0 += 16) {
        float4 av = *(const float4*)(A + (m0 + am) * K + k0 + ak);
        float4 bv = make_float4(0.f, 0.f, 0.f, 0.f);
        if (n0 + bn < N) bv = *(const float4*)(Bw + (k0 + bk) * N + n0 + bn);
        __syncthreads();
        As[ak + 0][am] = av.x;
        As[ak + 1][am] = av.y;
        As[ak + 2][am] = av.z;
        As[ak + 3][am] = av.w;
        *(float4*)&Bs[bk][bn] = bv;
        __syncthreads();
#pragma unroll
        for (int kk = 0; kk < 16; ++kk) {
            float4 a = *(const float4*)&As[kk][ty * 4];
            float4 bb = *(const float4*)&Bs[kk][tx * 4];
            float aa[4] = {a.x, a.y, a.z, a.w};
            float bbb[4] = {bb.x, bb.y, bb.z, bb.w};
#pragma unroll
            for (int i = 0; i < 4; ++i)
#pragma unroll
                for (int j = 0; j < 4; ++j)
                    acc[i][j] = fmaf(aa[i], bbb[j], acc[i][j]);
        }
    }
#pragma unroll
    for (int i = 0; i < 4; ++i) {
        int m = m0 + ty * 4 + i;
#pragma unroll
        for (int j = 0; j < 4; ++j) {
            int n = n0 + tx * 4 + j;
            if (n < N) {
                float v = acc[i][j] + bias[n];
                if (ACT == 0) v = fmaxf(v, 0.f);
                else          v = 1.f / (1.f + expf(-v));
                C[m * N + n] = v;
            }
        }
    }
}

// --------------------------------------------------------------------------
extern "C" void kernel_launch(void* const* d_in, const int* in_sizes, int n_in,
                              void* d_out, int out_size, void* d_ws, size_t ws_size,
                              hipStream_t stream) {
    const float* x   = (const float*)d_in[0];
    const float* w1  = (const float*)d_in[1];
    const float* b1  = (const float*)d_in[2];
    const float* pw  = (const float*)d_in[3];
    const float* pb  = (const float*)d_in[4];
    const float* rw  = (const float*)d_in[5];
    const float* dw1 = (const float*)d_in[6];
    const float* db1 = (const float*)d_in[7];
    const float* dw2 = (const float*)d_in[8];
    const float* db2 = (const float*)d_in[9];
    const float* dw3 = (const float*)d_in[10];
    const float* db3 = (const float*)d_in[11];
    float* out = (float*)d_out;
    char* wsb  = (char*)d_ws;
    if (ws_size < (size_t)WS_BYTES) return;

    h16*   hhi  = (h16*)(wsb + OFFB_HHI);
    h16*   hlo  = (h16*)(wsb + OFFB_HLO);
    h16*   wthi = (h16*)(wsb + OFFB_WTHI);
    h16*   wtlo = (h16*)(wsb + OFFB_WTLO);
    float* wt1  = (float*)(wsb + OFFB_WT1);
    float* Cbuf = (float*)(wsb + OFFB_C);
    float* u    = (float*)(wsb + OFFB_U);
    float* vbuf = (float*)(wsb + OFFB_V);
    float* msk  = (float*)(wsb + OFFB_MSK);
    float* d1   = (float*)(wsb + OFFB_D1);
    float* d2   = (float*)(wsb + OFFB_D2);

    transpose_w1<<<81, 256, 0, stream>>>(w1, wt1);
    split_pw<<<256, 256, 0, stream>>>(pw, wthi, wtlo);
    conv1_k<<<512, 448, 0, stream>>>(x, wt1, b1, hhi, hlo);
    init_C<<<18432, 256, 0, stream>>>(pb, Cbuf);
    prim_gemm_mfma<<<2304, 256, 0, stream>>>(hhi, hlo, wthi, wtlo, Cbuf);
    squash_k<<<2304, 256, 0, stream>>>(Cbuf, u);       // h dead from here on
    routing_k<<<5120, 384, 0, stream>>>(u, rw, vbuf);
    mask_k<<<2, 256, 0, stream>>>(vbuf, out, msk);
    dec_gemm<0><<<64, 256, 0, stream>>>(msk, dw1, db1, d1, 512, 512, 160);
    dec_gemm<0><<<128, 256, 0, stream>>>(d1, dw2, db2, d2, 512, 1024, 512);
    dec_gemm<1><<<104, 256, 0, stream>>>(d2, dw3, db3, out + 5120, 512, 784, 1024);
}

// Round 6
// 1538.122 us; speedup vs baseline: 3.1415x; 1.2297x over previous
//
#include <hip/hip_runtime.h>
#include <math.h>

// ---------------------------------------------------------------------------
// CapsuleNet forward (round 6): two-phase routing.
// Phase A (priors_k): priors[c,b,n,16] = u[b,n,:8] @ rw[c,n,:8,:16], fp16,
//   block per (c,n) -> rw read ONCE (was 512x per class).
// Phase B (routing2_k): register-resident 3-iter routing, reads priors
//   contiguously (73.7 KB per (c,b) block, each byte once).
// prim conv MFMA GEMM (BM=BN=128, splitK8, kt->XCD) unchanged from round 5.
// ---------------------------------------------------------------------------

typedef _Float16 h16;
typedef h16 frag8 __attribute__((ext_vector_type(8)));    // 8 halves = 16 B
typedef float f32x4 __attribute__((ext_vector_type(4)));

// workspace layout (BYTE offsets). Peak = 249,906,176 B.
#define OFFB_HHI   0L             // 52428800 halves = 104857600 B
#define OFFB_HLO   104857600L     // 52428800 halves
#define OFFB_WTHI  209715200L     // 5308416 halves = 10616832 B
#define OFFB_WTLO  220332032L     // 5308416 halves
#define OFFB_WT1   230948864L     // 20736 floats = 82944 B
#define OFFB_C     231031808L     // 4718592 floats -> end 249906176
#define WS_BYTES   249906176L
// aliased into dead h region after prim_gemm:
#define OFFB_PRI   0L             // 94371840 halves = 188743680 B (priors fp16)
#define OFFB_UT    188743680L     // 4718592 floats = 18874368 B -> 207618048 OK
// aliased into dead wt region after prim_gemm:
#define OFFB_V     209715200L     // 81920 floats
#define OFFB_MSK   210042880L     // 81920 floats
#define OFFB_D1    210370560L     // 262144 floats
#define OFFB_D2    211419136L     // 524288 floats -> 213516288 OK (< 230948864)

// --------------------------------------------------------------------------
__global__ void transpose_w1(const float* __restrict__ w, float* __restrict__ wt) {
    int i = blockIdx.x * 256 + threadIdx.x;          // 20736 exact
    int k = i >> 8, oc = i & 255;
    wt[i] = w[oc * 81 + k];
}

// prim weights -> B^T fp16 hi/lo: wt[oc][k], k = tap*256+ic. LDS transpose.
__global__ __launch_bounds__(256) void split_pw(const float* __restrict__ w,
                                                h16* __restrict__ whi,
                                                h16* __restrict__ wlo) {
    __shared__ float s[2592];                        // 32 ic x 81 taps
    int oc = blockIdx.x;
    int tid = threadIdx.x;
    long src0 = (long)oc * 20736;
    long dst0 = (long)oc * 20736;
    for (int ch = 0; ch < 8; ++ch) {
        int ic0 = ch * 32;
        __syncthreads();
        for (int e = tid; e < 2592; e += 256) s[e] = w[src0 + ic0 * 81 + e];
        __syncthreads();
        for (int e = tid; e < 2592; e += 256) {
            int tap = e >> 5, icf = e & 31;
            float v = s[icf * 81 + tap];
            h16 hi = (h16)v;
            long d = dst0 + tap * 256 + ic0 + icf;
            whi[d] = hi;
            wlo[d] = (h16)(v - (float)hi);
        }
    }
}

// C pre-fill with bias (split-K zero-init)
__global__ void init_C(const float* __restrict__ bias, float* __restrict__ C) {
    int i = blockIdx.x * 256 + threadIdx.x;          // 4718592 exact
    C[i] = bias[i & 255];
}

// --------------------------------------------------------------------------
// conv1: x[b][28][28] * w -> h fp16 hi/lo, NHWC [b][y][x][oc], ReLU
__global__ __launch_bounds__(448) void conv1_k(const float* __restrict__ x,
                                               const float* __restrict__ wt1,
                                               const float* __restrict__ bias,
                                               h16* __restrict__ hhi,
                                               h16* __restrict__ hlo) {
    __shared__ float xs[784];
    int b = blockIdx.x;
    int tid = threadIdx.x;
    for (int i = tid; i < 784; i += 448) xs[i] = x[b * 784 + i];
    __syncthreads();
    if (tid >= 400) return;
    int oy = tid / 20, ox = tid - oy * 20;
    int xbase = oy * 28 + ox;
    long hb = ((long)(b * 20 + oy) * 20 + ox) * 256;
    for (int ocg = 0; ocg < 16; ++ocg) {
        int oc0 = ocg * 16;
        float acc[16];
#pragma unroll
        for (int j = 0; j < 16; ++j) acc[j] = bias[oc0 + j];
#pragma unroll
        for (int ky = 0; ky < 9; ++ky) {
#pragma unroll
            for (int kx = 0; kx < 9; ++kx) {
                float xv = xs[xbase + ky * 28 + kx];
                const float* wr = wt1 + (ky * 9 + kx) * 256 + oc0;
#pragma unroll
                for (int j = 0; j < 16; ++j) acc[j] = fmaf(wr[j], xv, acc[j]);
            }
        }
        frag8 h0, h1, l0, l1;
#pragma unroll
        for (int j = 0; j < 8; ++j) {
            float v0 = fmaxf(acc[j], 0.f);
            float v1 = fmaxf(acc[j + 8], 0.f);
            h16 a = (h16)v0, bb = (h16)v1;
            h0[j] = a; l0[j] = (h16)(v0 - (float)a);
            h1[j] = bb; l1[j] = (h16)(v1 - (float)bb);
        }
        *(frag8*)(hhi + hb + oc0)     = h0;
        *(frag8*)(hhi + hb + oc0 + 8) = h1;
        *(frag8*)(hlo + hb + oc0)     = l0;
        *(frag8*)(hlo + hb + oc0 + 8) = l1;
    }
}

// --------------------------------------------------------------------------
// prim conv MFMA GEMM: BM=128 BN=128 BK=32, split-K x8, atomic accumulate.
#define LDK 40
__global__ __launch_bounds__(256, 2) void prim_gemm_mfma(
        const h16* __restrict__ Ahi, const h16* __restrict__ Alo,
        const h16* __restrict__ Bhi, const h16* __restrict__ Blo,
        float* __restrict__ C) {
    __shared__ h16 As[2][128][LDK];
    __shared__ h16 Bs[2][128][LDK];
    int tid = threadIdx.x;
    int bx = blockIdx.x;                  // 2304 blocks
    int kt = bx & 7;
    int nt = (bx >> 3) & 1;
    int mt = bx >> 4;                     // 0..143
    int n0 = nt * 128;
    int kb0 = kt * 81;

    int wave = tid >> 6;
    int wm = wave >> 1, wn = wave & 1;
    int lane = tid & 63;
    int lm = lane & 15, quad = lane >> 4;

    int ra = tid >> 1;
    int sa = (tid & 1) * 16;
    int ma = mt * 128 + ra;
    int b = ma / 36, pos = ma - b * 36;
    int oy = pos / 6, ox = pos - oy * 6;
    long abase = ((long)(b * 20 + 2 * oy) * 20 + 2 * ox) * 256 + sa;
    long bbase = (long)(n0 + ra) * 20736 + sa;

    float4 pa0h, pa1h, pa0l, pa1l, pb0h, pb1h, pb0l, pb1l;
    auto gload = [&](int kb) {
        int tap = kb >> 3;
        int ic0 = (kb & 7) << 5;
        int ky = tap / 9, kx = tap - ky * 9;
        long aoff = abase + (ky * 20 + kx) * 256 + ic0;
        pa0h = *(const float4*)(Ahi + aoff);
        pa1h = *(const float4*)(Ahi + aoff + 8);
        pa0l = *(const float4*)(Alo + aoff);
        pa1l = *(const float4*)(Alo + aoff + 8);
        long boff = bbase + (long)kb * 32;
        pb0h = *(const float4*)(Bhi + boff);
        pb1h = *(const float4*)(Bhi + boff + 8);
        pb0l = *(const float4*)(Blo + boff);
        pb1l = *(const float4*)(Blo + boff + 8);
    };

    f32x4 acc[4][4];
#pragma unroll
    for (int i = 0; i < 4; ++i)
#pragma unroll
        for (int j = 0; j < 4; ++j) acc[i][j] = (f32x4){0.f, 0.f, 0.f, 0.f};

    gload(kb0);
    for (int it = 0; it < 81; ++it) {
        __syncthreads();
        *(float4*)&As[0][ra][sa]     = pa0h;
        *(float4*)&As[0][ra][sa + 8] = pa1h;
        *(float4*)&As[1][ra][sa]     = pa0l;
        *(float4*)&As[1][ra][sa + 8] = pa1l;
        *(float4*)&Bs[0][ra][sa]     = pb0h;
        *(float4*)&Bs[0][ra][sa + 8] = pb1h;
        *(float4*)&Bs[1][ra][sa]     = pb0l;
        *(float4*)&Bs[1][ra][sa + 8] = pb1l;
        __syncthreads();
        if (it + 1 < 81) gload(kb0 + it + 1);

        frag8 ah[4], al[4], bh[4], bl[4];
#pragma unroll
        for (int mi = 0; mi < 4; ++mi) {
            int row = wm * 64 + mi * 16 + lm;
            ah[mi] = *(const frag8*)&As[0][row][quad * 8];
            al[mi] = *(const frag8*)&As[1][row][quad * 8];
        }
#pragma unroll
        for (int ni = 0; ni < 4; ++ni) {
            int col = wn * 64 + ni * 16 + lm;
            bh[ni] = *(const frag8*)&Bs[0][col][quad * 8];
            bl[ni] = *(const frag8*)&Bs[1][col][quad * 8];
        }
#pragma unroll
        for (int mi = 0; mi < 4; ++mi)
#pragma unroll
            for (int ni = 0; ni < 4; ++ni) {
                acc[mi][ni] = __builtin_amdgcn_mfma_f32_16x16x32_f16(
                    ah[mi], bh[ni], acc[mi][ni], 0, 0, 0);
                acc[mi][ni] = __builtin_amdgcn_mfma_f32_16x16x32_f16(
                    ah[mi], bl[ni], acc[mi][ni], 0, 0, 0);
                acc[mi][ni] = __builtin_amdgcn_mfma_f32_16x16x32_f16(
                    al[mi], bh[ni], acc[mi][ni], 0, 0, 0);
            }
    }

#pragma unroll
    for (int ni = 0; ni < 4; ++ni) {
        int n = n0 + wn * 64 + ni * 16 + lm;
#pragma unroll
        for (int mi = 0; mi < 4; ++mi) {
            int m = mt * 128 + wm * 64 + mi * 16 + quad * 4;
#pragma unroll
            for (int r = 0; r < 4; ++r)
                atomicAdd(&C[(long)(m + r) * 256 + n], acc[mi][ni][r]);
        }
    }
}

// --------------------------------------------------------------------------
// squash: C[(b*36+pos)][256] -> ut[n][b][8], n = ci*36+pos (transposed for
// priors_k's coalesced b-major reads).
__global__ void squash_k(const float* __restrict__ C, float* __restrict__ ut) {
    int t = blockIdx.x * 256 + threadIdx.x;          // 589824 exact
    int row = t >> 5;                                 // (b*36+pos)
    int ci = t & 31;
    int b = row / 36, pos = row - b * 36;
    const float* src = C + (long)row * 256 + ci;
    float v[8]; float sn = 0.f;
#pragma unroll
    for (int i = 0; i < 8; ++i) { v[i] = src[i * 32]; sn = fmaf(v[i], v[i], sn); }
    float scale = (sn / (1.f + sn)) / sqrtf(sn);
    float* dst = ut + ((long)(ci * 36 + pos) * 512 + b) * 8;
    float4 o0 = make_float4(v[0]*scale, v[1]*scale, v[2]*scale, v[3]*scale);
    float4 o1 = make_float4(v[4]*scale, v[5]*scale, v[6]*scale, v[7]*scale);
    *(float4*)(dst) = o0;
    *(float4*)(dst + 4) = o1;
}

// --------------------------------------------------------------------------
// Phase A: priors[c,b,n,:16] = ut[n,b,:8] @ rw[c,n,:8,:16], fp16 out.
// Block per (c,n): rw tap loaded once to LDS; 2 b's per thread.
__global__ __launch_bounds__(256) void priors_k(const float* __restrict__ ut,
                                                const float* __restrict__ rw,
                                                h16* __restrict__ priors) {
    int bid = blockIdx.x;                 // 11520 = 10*1152
    int c = bid / 1152, n = bid - c * 1152;
    __shared__ float w[128];
    int tid = threadIdx.x;
    if (tid < 128) w[tid] = rw[((long)c * 1152 + n) * 128 + tid];
    __syncthreads();
#pragma unroll
    for (int r = 0; r < 2; ++r) {
        int b = tid + r * 256;
        const float4* up = (const float4*)(ut + ((long)n * 512 + b) * 8);
        float4 ua = up[0], ub = up[1];
        float uu[8] = {ua.x, ua.y, ua.z, ua.w, ub.x, ub.y, ub.z, ub.w};
        float o[16];
#pragma unroll
        for (int j = 0; j < 16; ++j) o[j] = 0.f;
#pragma unroll
        for (int i = 0; i < 8; ++i)
#pragma unroll
            for (int j = 0; j < 16; ++j)
                o[j] = fmaf(uu[i], w[i * 16 + j], o[j]);
        frag8 p0, p1;
#pragma unroll
        for (int j = 0; j < 8; ++j) { p0[j] = (h16)o[j]; p1[j] = (h16)o[j + 8]; }
        h16* dst = priors + ((long)(c * 512 + b) * 1152 + n) * 16;
        *(frag8*)dst = p0;
        *(frag8*)(dst + 8) = p1;
    }
}

// --------------------------------------------------------------------------
// Phase B: 3-iter routing from materialized fp16 priors. Block per (c,b);
// each block reads its contiguous 73.7 KB slice exactly once.
__global__ __launch_bounds__(384) void routing2_k(const h16* __restrict__ priors,
                                                  float* __restrict__ vbuf) {
    int c = blockIdx.x >> 9;
    int b = blockIdx.x & 511;
    int tid = threadIdx.x;
    int wid = tid >> 6;
    int lane = tid & 63;
    __shared__ float wred[6][20];

    float pr[3][16];
#pragma unroll
    for (int r = 0; r < 3; ++r) {
        int n = tid + r * 384;
        const h16* pp = priors + ((long)(c * 512 + b) * 1152 + n) * 16;
        frag8 p0 = *(const frag8*)pp;
        frag8 p1 = *(const frag8*)(pp + 8);
#pragma unroll
        for (int o = 0; o < 8; ++o) { pr[r][o] = (float)p0[o]; pr[r][o + 8] = (float)p1[o]; }
    }

    float l0 = 0.f, l1 = 0.f, l2 = 0.f;
    float vout[16];
    for (int it = 0; it < 3; ++it) {
        float lm = fmaxf(fmaxf(l0, l1), l2);
#pragma unroll
        for (int m = 32; m >= 1; m >>= 1) lm = fmaxf(lm, __shfl_xor(lm, m));
        if (lane == 0) wred[wid][17] = lm;
        __syncthreads();
        float maxv = wred[0][17];
#pragma unroll
        for (int w = 1; w < 6; ++w) maxv = fmaxf(maxv, wred[w][17]);

        float e0 = expf(l0 - maxv), e1 = expf(l1 - maxv), e2 = expf(l2 - maxv);
        float red[17];
#pragma unroll
        for (int o = 0; o < 16; ++o)
            red[o] = fmaf(e0, pr[0][o], fmaf(e1, pr[1][o], e2 * pr[2][o]));
        red[16] = e0 + e1 + e2;
#pragma unroll
        for (int o = 0; o < 17; ++o) {
#pragma unroll
            for (int m = 32; m >= 1; m >>= 1) red[o] += __shfl_xor(red[o], m);
        }
        __syncthreads();
        if (lane == 0) {
#pragma unroll
            for (int o = 0; o < 17; ++o) wred[wid][o] = red[o];
        }
        __syncthreads();
        float sv[17];
#pragma unroll
        for (int o = 0; o < 17; ++o) {
            float tacc = wred[0][o];
#pragma unroll
            for (int w = 1; w < 6; ++w) tacc += wred[w][o];
            sv[o] = tacc;
        }
        float inv = 1.f / sv[16];
        float sn = 0.f;
#pragma unroll
        for (int o = 0; o < 16; ++o) { float s = sv[o] * inv; sn = fmaf(s, s, sn); }
        float scale = (sn / (1.f + sn)) / sqrtf(sn);
#pragma unroll
        for (int o = 0; o < 16; ++o) vout[o] = sv[o] * inv * scale;

        if (it < 2) {
            float d0 = 0.f, d1 = 0.f, d2 = 0.f;
#pragma unroll
            for (int o = 0; o < 16; ++o) {
                d0 = fmaf(pr[0][o], vout[o], d0);
                d1 = fmaf(pr[1][o], vout[o], d1);
                d2 = fmaf(pr[2][o], vout[o], d2);
            }
            l0 += d0; l1 += d1; l2 += d2;
        }
    }
    if (tid < 16) vbuf[(b * 10 + c) * 16 + tid] = vout[tid];
}

// --------------------------------------------------------------------------
__global__ void mask_k(const float* __restrict__ vbuf, float* __restrict__ out,
                       float* __restrict__ masked) {
    int b = blockIdx.x * 256 + threadIdx.x;
    if (b >= 512) return;
    const float* vp = vbuf + b * 160;
    float cls[10]; int best = 0; float bv = -1.f;
#pragma unroll
    for (int cc = 0; cc < 10; ++cc) {
        float sn = 0.f;
#pragma unroll
        for (int o = 0; o < 16; ++o) { float v = vp[cc * 16 + o]; sn = fmaf(v, v, sn); }
        cls[cc] = sqrtf(sn);
        if (cls[cc] > bv) { bv = cls[cc]; best = cc; }
    }
#pragma unroll
    for (int cc = 0; cc < 10; ++cc) {
        out[b * 10 + cc] = (cc == best) ? 1.f : 0.f;
        out[406528 + b * 10 + cc] = cls[cc];
    }
#pragma unroll
    for (int cc = 0; cc < 10; ++cc) {
        float keep = (cc == best) ? 1.f : 0.f;
#pragma unroll
        for (int o = 0; o < 16; ++o)
            masked[b * 160 + cc * 16 + o] = keep * vp[cc * 16 + o];
    }
}

// --------------------------------------------------------------------------
template <int ACT>
__global__ __launch_bounds__(256) void dec_gemm(const float* __restrict__ A,
                                                const float* __restrict__ Bw,
                                                const float* __restrict__ bias,
                                                float* __restrict__ C,
                                                int M, int N, int K) {
    __shared__ float As[16][68];
    __shared__ float Bs[16][68];
    int ntiles = (N + 63) >> 6;
    int mt = blockIdx.x / ntiles, nt = blockIdx.x - mt * ntiles;
    int m0 = mt * 64, n0 = nt * 64;
    int tid = threadIdx.x;
    int tx = tid & 15, ty = tid >> 4;
    int am = tid >> 2, ak = (tid & 3) * 4;
    int bk = tid >> 4, bn = (tid & 15) * 4;
    float acc[4][4];
#pragma unroll
    for (int i = 0; i < 4; ++i)
#pragma unroll
        for (int j = 0; j < 4; ++j) acc[i][j] = 0.f;

    for (int k0 = 0; k0 < K; k0 += 16) {
        float4 av = *(const float4*)(A + (m0 + am) * K + k0 + ak);
        float4 bv = make_float4(0.f, 0.f, 0.f, 0.f);
        if (n0 + bn < N) bv = *(const float4*)(Bw + (k0 + bk) * N + n0 + bn);
        __syncthreads();
        As[ak + 0][am] = av.x;
        As[ak + 1][am] = av.y;
        As[ak + 2][am] = av.z;
        As[ak + 3][am] = av.w;
        *(float4*)&Bs[bk][bn] = bv;
        __syncthreads();
#pragma unroll
        for (int kk = 0; kk < 16; ++kk) {
            float4 a = *(const float4*)&As[kk][ty * 4];
            float4 bb = *(const float4*)&Bs[kk][tx * 4];
            float aa[4] = {a.x, a.y, a.z, a.w};
            float bbb[4] = {bb.x, bb.y, bb.z, bb.w};
#pragma unroll
            for (int i = 0; i < 4; ++i)
#pragma unroll
                for (int j = 0; j < 4; ++j)
                    acc[i][j] = fmaf(aa[i], bbb[j], acc[i][j]);
        }
    }
#pragma unroll
    for (int i = 0; i < 4; ++i) {
        int m = m0 + ty * 4 + i;
#pragma unroll
        for (int j = 0; j < 4; ++j) {
            int n = n0 + tx * 4 + j;
            if (n < N) {
                float v = acc[i][j] + bias[n];
                if (ACT == 0) v = fmaxf(v, 0.f);
                else          v = 1.f / (1.f + expf(-v));
                C[m * N + n] = v;
            }
        }
    }
}

// --------------------------------------------------------------------------
extern "C" void kernel_launch(void* const* d_in, const int* in_sizes, int n_in,
                              void* d_out, int out_size, void* d_ws, size_t ws_size,
                              hipStream_t stream) {
    const float* x   = (const float*)d_in[0];
    const float* w1  = (const float*)d_in[1];
    const float* b1  = (const float*)d_in[2];
    const float* pw  = (const float*)d_in[3];
    const float* pb  = (const float*)d_in[4];
    const float* rw  = (const float*)d_in[5];
    const float* dw1 = (const float*)d_in[6];
    const float* db1 = (const float*)d_in[7];
    const float* dw2 = (const float*)d_in[8];
    const float* db2 = (const float*)d_in[9];
    const float* dw3 = (const float*)d_in[10];
    const float* db3 = (const float*)d_in[11];
    float* out = (float*)d_out;
    char* wsb  = (char*)d_ws;
    if (ws_size < (size_t)WS_BYTES) return;

    h16*   hhi  = (h16*)(wsb + OFFB_HHI);
    h16*   hlo  = (h16*)(wsb + OFFB_HLO);
    h16*   wthi = (h16*)(wsb + OFFB_WTHI);
    h16*   wtlo = (h16*)(wsb + OFFB_WTLO);
    float* wt1  = (float*)(wsb + OFFB_WT1);
    float* Cbuf = (float*)(wsb + OFFB_C);
    h16*   pri  = (h16*)(wsb + OFFB_PRI);
    float* ut   = (float*)(wsb + OFFB_UT);
    float* vbuf = (float*)(wsb + OFFB_V);
    float* msk  = (float*)(wsb + OFFB_MSK);
    float* d1   = (float*)(wsb + OFFB_D1);
    float* d2   = (float*)(wsb + OFFB_D2);

    transpose_w1<<<81, 256, 0, stream>>>(w1, wt1);
    split_pw<<<256, 256, 0, stream>>>(pw, wthi, wtlo);
    conv1_k<<<512, 448, 0, stream>>>(x, wt1, b1, hhi, hlo);
    init_C<<<18432, 256, 0, stream>>>(pb, Cbuf);
    prim_gemm_mfma<<<2304, 256, 0, stream>>>(hhi, hlo, wthi, wtlo, Cbuf);
    squash_k<<<2304, 256, 0, stream>>>(Cbuf, ut);      // h region dead now
    priors_k<<<11520, 256, 0, stream>>>(ut, rw, pri);
    routing2_k<<<5120, 384, 0, stream>>>(pri, vbuf);
    mask_k<<<2, 256, 0, stream>>>(vbuf, out, msk);
    dec_gemm<0><<<64, 256, 0, stream>>>(msk, dw1, db1, d1, 512, 512, 160);
    dec_gemm<0><<<128, 256, 0, stream>>>(d1, dw2, db2, d2, 512, 1024, 512);
    dec_gemm<1><<<104, 256, 0, stream>>>(d2, dw3, db3, out + 5120, 512, 784, 1024);
}

// Round 7
// 1144.246 us; speedup vs baseline: 4.2229x; 1.3442x over previous
//
#include <hip/hip_runtime.h>
#include <math.h>

// ---------------------------------------------------------------------------
// CapsuleNet forward (round 7): single-pass fp16 prim GEMM.
// Rationale: routing averages 1152 nodes -> per-element fp16 rounding noise
// at the prim output damps ~2000x before the outputs (measured: fp16 priors
// moved absmax only 6e-8 -> 2.4e-7). So the hi/lo split correction passes
// are unnecessary; 1 MFMA pass, half the staging bytes, half the LDS.
// Two-phase routing (priors_k + routing2_k) unchanged from round 6.
// ---------------------------------------------------------------------------

typedef _Float16 h16;
typedef h16 frag8 __attribute__((ext_vector_type(8)));    // 8 halves = 16 B
typedef float f32x4 __attribute__((ext_vector_type(4)));

// workspace layout (BYTE offsets). Peak unchanged (lo regions now unused).
#define OFFB_HHI   0L             // 52428800 halves = 104857600 B
#define OFFB_WTHI  209715200L     // 5308416 halves = 10616832 B
#define OFFB_WT1   230948864L     // 20736 floats = 82944 B
#define OFFB_C     231031808L     // 4718592 floats -> end 249906176
#define WS_BYTES   249906176L
// aliased into dead h region after prim_gemm:
#define OFFB_PRI   0L             // 94371840 halves = 188743680 B (priors fp16)
#define OFFB_UT    188743680L     // 4718592 floats -> 207618048 OK
// aliased into dead wt region after prim_gemm:
#define OFFB_V     209715200L     // 81920 floats
#define OFFB_MSK   210042880L     // 81920 floats
#define OFFB_D1    210370560L     // 262144 floats
#define OFFB_D2    211419136L     // 524288 floats -> 213516288 OK

// --------------------------------------------------------------------------
__global__ void transpose_w1(const float* __restrict__ w, float* __restrict__ wt) {
    int i = blockIdx.x * 256 + threadIdx.x;          // 20736 exact
    int k = i >> 8, oc = i & 255;
    wt[i] = w[oc * 81 + k];
}

// prim weights -> B^T fp16: wt[oc][k], k = tap*256+ic. LDS transpose.
__global__ __launch_bounds__(256) void split_pw(const float* __restrict__ w,
                                                h16* __restrict__ whi) {
    __shared__ float s[2592];                        // 32 ic x 81 taps
    int oc = blockIdx.x;
    int tid = threadIdx.x;
    long src0 = (long)oc * 20736;
    long dst0 = (long)oc * 20736;
    for (int ch = 0; ch < 8; ++ch) {
        int ic0 = ch * 32;
        __syncthreads();
        for (int e = tid; e < 2592; e += 256) s[e] = w[src0 + ic0 * 81 + e];
        __syncthreads();
        for (int e = tid; e < 2592; e += 256) {
            int tap = e >> 5, icf = e & 31;
            whi[dst0 + tap * 256 + ic0 + icf] = (h16)s[icf * 81 + tap];
        }
    }
}

// C pre-fill with bias (split-K zero-init)
__global__ void init_C(const float* __restrict__ bias, float* __restrict__ C) {
    int i = blockIdx.x * 256 + threadIdx.x;          // 4718592 exact
    C[i] = bias[i & 255];
}

// --------------------------------------------------------------------------
// conv1: x[b][28][28] * w -> h fp16, NHWC [b][y][x][oc], ReLU
__global__ __launch_bounds__(448) void conv1_k(const float* __restrict__ x,
                                               const float* __restrict__ wt1,
                                               const float* __restrict__ bias,
                                               h16* __restrict__ hhi) {
    __shared__ float xs[784];
    int b = blockIdx.x;
    int tid = threadIdx.x;
    for (int i = tid; i < 784; i += 448) xs[i] = x[b * 784 + i];
    __syncthreads();
    if (tid >= 400) return;
    int oy = tid / 20, ox = tid - oy * 20;
    int xbase = oy * 28 + ox;
    long hb = ((long)(b * 20 + oy) * 20 + ox) * 256;
    for (int ocg = 0; ocg < 16; ++ocg) {
        int oc0 = ocg * 16;
        float acc[16];
#pragma unroll
        for (int j = 0; j < 16; ++j) acc[j] = bias[oc0 + j];
#pragma unroll
        for (int ky = 0; ky < 9; ++ky) {
#pragma unroll
            for (int kx = 0; kx < 9; ++kx) {
                float xv = xs[xbase + ky * 28 + kx];
                const float* wr = wt1 + (ky * 9 + kx) * 256 + oc0;
#pragma unroll
                for (int j = 0; j < 16; ++j) acc[j] = fmaf(wr[j], xv, acc[j]);
            }
        }
        frag8 h0, h1;
#pragma unroll
        for (int j = 0; j < 8; ++j) {
            h0[j] = (h16)fmaxf(acc[j], 0.f);
            h1[j] = (h16)fmaxf(acc[j + 8], 0.f);
        }
        *(frag8*)(hhi + hb + oc0)     = h0;
        *(frag8*)(hhi + hb + oc0 + 8) = h1;
    }
}

// --------------------------------------------------------------------------
// prim conv MFMA GEMM: BM=128 BN=128 BK=32, split-K x8 (kt -> XCD), fp16
// single pass, atomic accumulate into bias-prefilled C.
#define LDK 40
__global__ __launch_bounds__(256, 4) void prim_gemm_mfma(
        const h16* __restrict__ Ahi, const h16* __restrict__ Bhi,
        float* __restrict__ C) {
    __shared__ h16 As[128][LDK];
    __shared__ h16 Bs[128][LDK];
    int tid = threadIdx.x;
    int bx = blockIdx.x;                  // 2304 blocks
    int kt = bx & 7;
    int nt = (bx >> 3) & 1;
    int mt = bx >> 4;                     // 0..143
    int n0 = nt * 128;
    int kb0 = kt * 81;

    int wave = tid >> 6;
    int wm = wave >> 1, wn = wave & 1;
    int lane = tid & 63;
    int lm = lane & 15, quad = lane >> 4;

    int ra = tid >> 1;
    int sa = (tid & 1) * 16;
    int ma = mt * 128 + ra;
    int b = ma / 36, pos = ma - b * 36;
    int oy = pos / 6, ox = pos - oy * 6;
    long abase = ((long)(b * 20 + 2 * oy) * 20 + 2 * ox) * 256 + sa;
    long bbase = (long)(n0 + ra) * 20736 + sa;

    float4 pa0, pa1, pb0, pb1;
    auto gload = [&](int kb) {
        int tap = kb >> 3;
        int ic0 = (kb & 7) << 5;
        int ky = tap / 9, kx = tap - ky * 9;
        long aoff = abase + (ky * 20 + kx) * 256 + ic0;
        pa0 = *(const float4*)(Ahi + aoff);
        pa1 = *(const float4*)(Ahi + aoff + 8);
        long boff = bbase + (long)kb * 32;
        pb0 = *(const float4*)(Bhi + boff);
        pb1 = *(const float4*)(Bhi + boff + 8);
    };

    f32x4 acc[4][4];
#pragma unroll
    for (int i = 0; i < 4; ++i)
#pragma unroll
        for (int j = 0; j < 4; ++j) acc[i][j] = (f32x4){0.f, 0.f, 0.f, 0.f};

    gload(kb0);
    for (int it = 0; it < 81; ++it) {
        __syncthreads();
        *(float4*)&As[ra][sa]     = pa0;
        *(float4*)&As[ra][sa + 8] = pa1;
        *(float4*)&Bs[ra][sa]     = pb0;
        *(float4*)&Bs[ra][sa + 8] = pb1;
        __syncthreads();
        if (it + 1 < 81) gload(kb0 + it + 1);

        frag8 ah[4], bh[4];
#pragma unroll
        for (int mi = 0; mi < 4; ++mi) {
            int row = wm * 64 + mi * 16 + lm;
            ah[mi] = *(const frag8*)&As[row][quad * 8];
        }
#pragma unroll
        for (int ni = 0; ni < 4; ++ni) {
            int col = wn * 64 + ni * 16 + lm;
            bh[ni] = *(const frag8*)&Bs[col][quad * 8];
        }
#pragma unroll
        for (int mi = 0; mi < 4; ++mi)
#pragma unroll
            for (int ni = 0; ni < 4; ++ni)
                acc[mi][ni] = __builtin_amdgcn_mfma_f32_16x16x32_f16(
                    ah[mi], bh[ni], acc[mi][ni], 0, 0, 0);
    }

    // epilogue: C/D layout col = lane&15, row = quad*4 + reg; atomic split-K
#pragma unroll
    for (int ni = 0; ni < 4; ++ni) {
        int n = n0 + wn * 64 + ni * 16 + lm;
#pragma unroll
        for (int mi = 0; mi < 4; ++mi) {
            int m = mt * 128 + wm * 64 + mi * 16 + quad * 4;
#pragma unroll
            for (int r = 0; r < 4; ++r)
                atomicAdd(&C[(long)(m + r) * 256 + n], acc[mi][ni][r]);
        }
    }
}

// --------------------------------------------------------------------------
// squash: C[(b*36+pos)][256] -> ut[n][b][8], n = ci*36+pos.
__global__ void squash_k(const float* __restrict__ C, float* __restrict__ ut) {
    int t = blockIdx.x * 256 + threadIdx.x;          // 589824 exact
    int row = t >> 5;                                 // (b*36+pos)
    int ci = t & 31;
    int b = row / 36, pos = row - b * 36;
    const float* src = C + (long)row * 256 + ci;
    float v[8]; float sn = 0.f;
#pragma unroll
    for (int i = 0; i < 8; ++i) { v[i] = src[i * 32]; sn = fmaf(v[i], v[i], sn); }
    float scale = (sn / (1.f + sn)) / sqrtf(sn);
    float* dst = ut + ((long)(ci * 36 + pos) * 512 + b) * 8;
    float4 o0 = make_float4(v[0]*scale, v[1]*scale, v[2]*scale, v[3]*scale);
    float4 o1 = make_float4(v[4]*scale, v[5]*scale, v[6]*scale, v[7]*scale);
    *(float4*)(dst) = o0;
    *(float4*)(dst + 4) = o1;
}

// --------------------------------------------------------------------------
// Phase A: priors[c,b,n,:16] = ut[n,b,:8] @ rw[c,n,:8,:16], fp16 out.
__global__ __launch_bounds__(256) void priors_k(const float* __restrict__ ut,
                                                const float* __restrict__ rw,
                                                h16* __restrict__ priors) {
    int bid = blockIdx.x;                 // 11520 = 10*1152
    int c = bid / 1152, n = bid - c * 1152;
    __shared__ float w[128];
    int tid = threadIdx.x;
    if (tid < 128) w[tid] = rw[((long)c * 1152 + n) * 128 + tid];
    __syncthreads();
#pragma unroll
    for (int r = 0; r < 2; ++r) {
        int b = tid + r * 256;
        const float4* up = (const float4*)(ut + ((long)n * 512 + b) * 8);
        float4 ua = up[0], ub = up[1];
        float uu[8] = {ua.x, ua.y, ua.z, ua.w, ub.x, ub.y, ub.z, ub.w};
        float o[16];
#pragma unroll
        for (int j = 0; j < 16; ++j) o[j] = 0.f;
#pragma unroll
        for (int i = 0; i < 8; ++i)
#pragma unroll
            for (int j = 0; j < 16; ++j)
                o[j] = fmaf(uu[i], w[i * 16 + j], o[j]);
        frag8 p0, p1;
#pragma unroll
        for (int j = 0; j < 8; ++j) { p0[j] = (h16)o[j]; p1[j] = (h16)o[j + 8]; }
        h16* dst = priors + ((long)(c * 512 + b) * 1152 + n) * 16;
        *(frag8*)dst = p0;
        *(frag8*)(dst + 8) = p1;
    }
}

// --------------------------------------------------------------------------
// Phase B: 3-iter routing from materialized fp16 priors. Block per (c,b).
__global__ __launch_bounds__(384) void routing2_k(const h16* __restrict__ priors,
                                                  float* __restrict__ vbuf) {
    int c = blockIdx.x >> 9;
    int b = blockIdx.x & 511;
    int tid = threadIdx.x;
    int wid = tid >> 6;
    int lane = tid & 63;
    __shared__ float wred[6][20];

    float pr[3][16];
#pragma unroll
    for (int r = 0; r < 3; ++r) {
        int n = tid + r * 384;
        const h16* pp = priors + ((long)(c * 512 + b) * 1152 + n) * 16;
        frag8 p0 = *(const frag8*)pp;
        frag8 p1 = *(const frag8*)(pp + 8);
#pragma unroll
        for (int o = 0; o < 8; ++o) { pr[r][o] = (float)p0[o]; pr[r][o + 8] = (float)p1[o]; }
    }

    float l0 = 0.f, l1 = 0.f, l2 = 0.f;
    float vout[16];
    for (int it = 0; it < 3; ++it) {
        float lm = fmaxf(fmaxf(l0, l1), l2);
#pragma unroll
        for (int m = 32; m >= 1; m >>= 1) lm = fmaxf(lm, __shfl_xor(lm, m));
        if (lane == 0) wred[wid][17] = lm;
        __syncthreads();
        float maxv = wred[0][17];
#pragma unroll
        for (int w = 1; w < 6; ++w) maxv = fmaxf(maxv, wred[w][17]);

        float e0 = expf(l0 - maxv), e1 = expf(l1 - maxv), e2 = expf(l2 - maxv);
        float red[17];
#pragma unroll
        for (int o = 0; o < 16; ++o)
            red[o] = fmaf(e0, pr[0][o], fmaf(e1, pr[1][o], e2 * pr[2][o]));
        red[16] = e0 + e1 + e2;
#pragma unroll
        for (int o = 0; o < 17; ++o) {
#pragma unroll
            for (int m = 32; m >= 1; m >>= 1) red[o] += __shfl_xor(red[o], m);
        }
        __syncthreads();
        if (lane == 0) {
#pragma unroll
            for (int o = 0; o < 17; ++o) wred[wid][o] = red[o];
        }
        __syncthreads();
        float sv[17];
#pragma unroll
        for (int o = 0; o < 17; ++o) {
            float tacc = wred[0][o];
#pragma unroll
            for (int w = 1; w < 6; ++w) tacc += wred[w][o];
            sv[o] = tacc;
        }
        float inv = 1.f / sv[16];
        float sn = 0.f;
#pragma unroll
        for (int o = 0; o < 16; ++o) { float s = sv[o] * inv; sn = fmaf(s, s, sn); }
        float scale = (sn / (1.f + sn)) / sqrtf(sn);
#pragma unroll
        for (int o = 0; o < 16; ++o) vout[o] = sv[o] * inv * scale;

        if (it < 2) {
            float d0 = 0.f, d1 = 0.f, d2 = 0.f;
#pragma unroll
            for (int o = 0; o < 16; ++o) {
                d0 = fmaf(pr[0][o], vout[o], d0);
                d1 = fmaf(pr[1][o], vout[o], d1);
                d2 = fmaf(pr[2][o], vout[o], d2);
            }
            l0 += d0; l1 += d1; l2 += d2;
        }
    }
    if (tid < 16) vbuf[(b * 10 + c) * 16 + tid] = vout[tid];
}

// --------------------------------------------------------------------------
__global__ void mask_k(const float* __restrict__ vbuf, float* __restrict__ out,
                       float* __restrict__ masked) {
    int b = blockIdx.x * 256 + threadIdx.x;
    if (b >= 512) return;
    const float* vp = vbuf + b * 160;
    float cls[10]; int best = 0; float bv = -1.f;
#pragma unroll
    for (int cc = 0; cc < 10; ++cc) {
        float sn = 0.f;
#pragma unroll
        for (int o = 0; o < 16; ++o) { float v = vp[cc * 16 + o]; sn = fmaf(v, v, sn); }
        cls[cc] = sqrtf(sn);
        if (cls[cc] > bv) { bv = cls[cc]; best = cc; }
    }
#pragma unroll
    for (int cc = 0; cc < 10; ++cc) {
        out[b * 10 + cc] = (cc == best) ? 1.f : 0.f;
        out[406528 + b * 10 + cc] = cls[cc];
    }
#pragma unroll
    for (int cc = 0; cc < 10; ++cc) {
        float keep = (cc == best) ? 1.f : 0.f;
#pragma unroll
        for (int o = 0; o < 16; ++o)
            masked[b * 160 + cc * 16 + o] = keep * vp[cc * 16 + o];
    }
}

// --------------------------------------------------------------------------
template <int ACT>
__global__ __launch_bounds__(256) void dec_gemm(const float* __restrict__ A,
                                                const float* __restrict__ Bw,
                                                const float* __restrict__ bias,
                                                float* __restrict__ C,
                                                int M, int N, int K) {
    __shared__ float As[16][68];
    __shared__ float Bs[16][68];
    int ntiles = (N + 63) >> 6;
    int mt = blockIdx.x / ntiles, nt = blockIdx.x - mt * ntiles;
    int m0 = mt * 64, n0 = nt * 64;
    int tid = threadIdx.x;
    int tx = tid & 15, ty = tid >> 4;
    int am = tid >> 2, ak = (tid & 3) * 4;
    int bk = tid >> 4, bn = (tid & 15) * 4;
    float acc[4][4];
#pragma unroll
    for (int i = 0; i < 4; ++i)
#pragma unroll
        for (int j = 0; j < 4; ++j) acc[i][j] = 0.f;

    for (int k0 = 0; k0 < K; k0 += 16) {
        float4 av = *(const float4*)(A + (m0 + am) * K + k0 + ak);
        float4 bv = make_float4(0.f, 0.f, 0.f, 0.f);
        if (n0 + bn < N) bv = *(const float4*)(Bw + (k0 + bk) * N + n0 + bn);
        __syncthreads();
        As[ak + 0][am] = av.x;
        As[ak + 1][am] = av.y;
        As[ak + 2][am] = av.z;
        As[ak + 3][am] = av.w;
        *(float4*)&Bs[bk][bn] = bv;
        __syncthreads();
#pragma unroll
        for (int kk = 0; kk < 16; ++kk) {
            float4 a = *(const float4*)&As[kk][ty * 4];
            float4 bb = *(const float4*)&Bs[kk][tx * 4];
            float aa[4] = {a.x, a.y, a.z, a.w};
            float bbb[4] = {bb.x, bb.y, bb.z, bb.w};
#pragma unroll
            for (int i = 0; i < 4; ++i)
#pragma unroll
                for (int j = 0; j < 4; ++j)
                    acc[i][j] = fmaf(aa[i], bbb[j], acc[i][j]);
        }
    }
#pragma unroll
    for (int i = 0; i < 4; ++i) {
        int m = m0 + ty * 4 + i;
#pragma unroll
        for (int j = 0; j < 4; ++j) {
            int n = n0 + tx * 4 + j;
            if (n < N) {
                float v = acc[i][j] + bias[n];
                if (ACT == 0) v = fmaxf(v, 0.f);
                else          v = 1.f / (1.f + expf(-v));
                C[m * N + n] = v;
            }
        }
    }
}

// --------------------------------------------------------------------------
extern "C" void kernel_launch(void* const* d_in, const int* in_sizes, int n_in,
                              void* d_out, int out_size, void* d_ws, size_t ws_size,
                              hipStream_t stream) {
    const float* x   = (const float*)d_in[0];
    const float* w1  = (const float*)d_in[1];
    const float* b1  = (const float*)d_in[2];
    const float* pw  = (const float*)d_in[3];
    const float* pb  = (const float*)d_in[4];
    const float* rw  = (const float*)d_in[5];
    const float* dw1 = (const float*)d_in[6];
    const float* db1 = (const float*)d_in[7];
    const float* dw2 = (const float*)d_in[8];
    const float* db2 = (const float*)d_in[9];
    const float* dw3 = (const float*)d_in[10];
    const float* db3 = (const float*)d_in[11];
    float* out = (float*)d_out;
    char* wsb  = (char*)d_ws;
    if (ws_size < (size_t)WS_BYTES) return;

    h16*   hhi  = (h16*)(wsb + OFFB_HHI);
    h16*   wthi = (h16*)(wsb + OFFB_WTHI);
    float* wt1  = (float*)(wsb + OFFB_WT1);
    float* Cbuf = (float*)(wsb + OFFB_C);
    h16*   pri  = (h16*)(wsb + OFFB_PRI);
    float* ut   = (float*)(wsb + OFFB_UT);
    float* vbuf = (float*)(wsb + OFFB_V);
    float* msk  = (float*)(wsb + OFFB_MSK);
    float* d1   = (float*)(wsb + OFFB_D1);
    float* d2   = (float*)(wsb + OFFB_D2);

    transpose_w1<<<81, 256, 0, stream>>>(w1, wt1);
    split_pw<<<256, 256, 0, stream>>>(pw, wthi);
    conv1_k<<<512, 448, 0, stream>>>(x, wt1, b1, hhi);
    init_C<<<18432, 256, 0, stream>>>(pb, Cbuf);
    prim_gemm_mfma<<<2304, 256, 0, stream>>>(hhi, wthi, Cbuf);
    squash_k<<<2304, 256, 0, stream>>>(Cbuf, ut);      // h region dead now
    priors_k<<<11520, 256, 0, stream>>>(ut, rw, pri);
    routing2_k<<<5120, 384, 0, stream>>>(pri, vbuf);
    mask_k<<<2, 256, 0, stream>>>(vbuf, out, msk);
    dec_gemm<0><<<64, 256, 0, stream>>>(msk, dw1, db1, d1, 512, 512, 160);
    dec_gemm<0><<<128, 256, 0, stream>>>(d1, dw2, db2, d2, 512, 1024, 512);
    dec_gemm<1><<<104, 256, 0, stream>>>(d2, dw3, db3, out + 5120, 512, 784, 1024);
}

// Round 8
// 1057.133 us; speedup vs baseline: 4.5709x; 1.0824x over previous
//
#include <hip/hip_runtime.h>
#include <math.h>

// ---------------------------------------------------------------------------
// CapsuleNet forward (round 8):
//  - prim GEMM on mfma_f32_32x32x16_f16 (8 MFMA/iter instead of 16)
//  - priors_k rewritten for coalesced reads+writes (32b x 8n thread tile)
//  - conv1_k preloads the 81-tap window into registers (kills LDS rereads)
// Everything else unchanged from round 7.
// ---------------------------------------------------------------------------

typedef _Float16 h16;
typedef h16 frag8 __attribute__((ext_vector_type(8)));    // 8 halves = 16 B
typedef float f32x4 __attribute__((ext_vector_type(4)));
typedef float f32x16 __attribute__((ext_vector_type(16)));

// workspace layout (BYTE offsets).
#define OFFB_HHI   0L             // 52428800 halves = 104857600 B
#define OFFB_WTHI  209715200L     // 5308416 halves = 10616832 B
#define OFFB_WT1   230948864L     // 20736 floats = 82944 B
#define OFFB_C     231031808L     // 4718592 floats -> end 249906176
#define WS_BYTES   249906176L
// aliased into dead h region after prim_gemm:
#define OFFB_PRI   0L             // 94371840 halves = 188743680 B (priors fp16)
#define OFFB_UT    188743680L     // 4718592 floats -> 207618048 OK
// aliased into dead wt region after prim_gemm:
#define OFFB_V     209715200L     // 81920 floats
#define OFFB_MSK   210042880L     // 81920 floats
#define OFFB_D1    210370560L     // 262144 floats
#define OFFB_D2    211419136L     // 524288 floats -> 213516288 OK

// --------------------------------------------------------------------------
__global__ void transpose_w1(const float* __restrict__ w, float* __restrict__ wt) {
    int i = blockIdx.x * 256 + threadIdx.x;          // 20736 exact
    int k = i >> 8, oc = i & 255;
    wt[i] = w[oc * 81 + k];
}

// prim weights -> B^T fp16: wt[oc][k], k = tap*256+ic. LDS transpose.
__global__ __launch_bounds__(256) void split_pw(const float* __restrict__ w,
                                                h16* __restrict__ whi) {
    __shared__ float s[2592];                        // 32 ic x 81 taps
    int oc = blockIdx.x;
    int tid = threadIdx.x;
    long src0 = (long)oc * 20736;
    long dst0 = (long)oc * 20736;
    for (int ch = 0; ch < 8; ++ch) {
        int ic0 = ch * 32;
        __syncthreads();
        for (int e = tid; e < 2592; e += 256) s[e] = w[src0 + ic0 * 81 + e];
        __syncthreads();
        for (int e = tid; e < 2592; e += 256) {
            int tap = e >> 5, icf = e & 31;
            whi[dst0 + tap * 256 + ic0 + icf] = (h16)s[icf * 81 + tap];
        }
    }
}

// C pre-fill with bias (split-K zero-init)
__global__ void init_C(const float* __restrict__ bias, float* __restrict__ C) {
    int i = blockIdx.x * 256 + threadIdx.x;          // 4718592 exact
    C[i] = bias[i & 255];
}

// --------------------------------------------------------------------------
// conv1: x[b][28][28] * w -> h fp16, NHWC [b][y][x][oc], ReLU.
// 81-tap window preloaded to registers; inner loop pure FMA.
__global__ __launch_bounds__(448) void conv1_k(const float* __restrict__ x,
                                               const float* __restrict__ wt1,
                                               const float* __restrict__ bias,
                                               h16* __restrict__ hhi) {
    __shared__ float xs[784];
    int b = blockIdx.x;
    int tid = threadIdx.x;
    for (int i = tid; i < 784; i += 448) xs[i] = x[b * 784 + i];
    __syncthreads();
    if (tid >= 400) return;
    int oy = tid / 20, ox = tid - oy * 20;
    int xbase = oy * 28 + ox;
    float xv[81];
#pragma unroll
    for (int ky = 0; ky < 9; ++ky)
#pragma unroll
        for (int kx = 0; kx < 9; ++kx)
            xv[ky * 9 + kx] = xs[xbase + ky * 28 + kx];
    long hb = ((long)(b * 20 + oy) * 20 + ox) * 256;
    for (int ocg = 0; ocg < 16; ++ocg) {
        int oc0 = ocg * 16;
        float acc[16];
#pragma unroll
        for (int j = 0; j < 16; ++j) acc[j] = bias[oc0 + j];
#pragma unroll
        for (int t = 0; t < 81; ++t) {
            const float* wr = wt1 + t * 256 + oc0;   // wave-uniform -> s_load
            float xt = xv[t];
#pragma unroll
            for (int j = 0; j < 16; ++j) acc[j] = fmaf(wr[j], xt, acc[j]);
        }
        frag8 h0, h1;
#pragma unroll
        for (int j = 0; j < 8; ++j) {
            h0[j] = (h16)fmaxf(acc[j], 0.f);
            h1[j] = (h16)fmaxf(acc[j + 8], 0.f);
        }
        *(frag8*)(hhi + hb + oc0)     = h0;
        *(frag8*)(hhi + hb + oc0 + 8) = h1;
    }
}

// --------------------------------------------------------------------------
// prim conv MFMA GEMM: BM=128 BN=128 BK=32, split-K x8 (kt -> XCD), fp16
// single pass, 32x32x16 MFMA, atomic accumulate into bias-prefilled C.
// Wave tile 64x64 = 2x2 of 32x32.
// A frag: m = lane&31, k = (lane>>5)*8 + j. B mirrored.
// C/D: col = lane&31, row = (reg&3) + 8*(reg>>2) + 4*(lane>>5).
#define LDK 40
__global__ __launch_bounds__(256, 4) void prim_gemm_mfma(
        const h16* __restrict__ Ahi, const h16* __restrict__ Bhi,
        float* __restrict__ C) {
    __shared__ h16 As[128][LDK];
    __shared__ h16 Bs[128][LDK];
    int tid = threadIdx.x;
    int bx = blockIdx.x;                  // 2304 blocks
    int kt = bx & 7;
    int nt = (bx >> 3) & 1;
    int mt = bx >> 4;                     // 0..143
    int n0 = nt * 128;
    int kb0 = kt * 81;

    int wave = tid >> 6;
    int wm = wave >> 1, wn = wave & 1;    // wave tile origin: (wm*64, wn*64)
    int lane = tid & 63;
    int lr = lane & 31, half = lane >> 5;

    int ra = tid >> 1;
    int sa = (tid & 1) * 16;
    int ma = mt * 128 + ra;
    int b = ma / 36, pos = ma - b * 36;
    int oy = pos / 6, ox = pos - oy * 6;
    long abase = ((long)(b * 20 + 2 * oy) * 20 + 2 * ox) * 256 + sa;
    long bbase = (long)(n0 + ra) * 20736 + sa;

    float4 pa0, pa1, pb0, pb1;
    auto gload = [&](int kb) {
        int tap = kb >> 3;
        int ic0 = (kb & 7) << 5;
        int ky = tap / 9, kx = tap - ky * 9;
        long aoff = abase + (ky * 20 + kx) * 256 + ic0;
        pa0 = *(const float4*)(Ahi + aoff);
        pa1 = *(const float4*)(Ahi + aoff + 8);
        long boff = bbase + (long)kb * 32;
        pb0 = *(const float4*)(Bhi + boff);
        pb1 = *(const float4*)(Bhi + boff + 8);
    };

    f32x16 acc[2][2];
#pragma unroll
    for (int i = 0; i < 2; ++i)
#pragma unroll
        for (int j = 0; j < 2; ++j)
#pragma unroll
            for (int r = 0; r < 16; ++r) acc[i][j][r] = 0.f;

    gload(kb0);
    for (int it = 0; it < 81; ++it) {
        __syncthreads();
        *(float4*)&As[ra][sa]     = pa0;
        *(float4*)&As[ra][sa + 8] = pa1;
        *(float4*)&Bs[ra][sa]     = pb0;
        *(float4*)&Bs[ra][sa + 8] = pb1;
        __syncthreads();
        if (it + 1 < 81) gload(kb0 + it + 1);

        frag8 af[2][2], bf[2][2];         // [ks][mi/ni]
#pragma unroll
        for (int ks = 0; ks < 2; ++ks) {
            int kc = ks * 16 + half * 8;
#pragma unroll
            for (int mi = 0; mi < 2; ++mi)
                af[ks][mi] = *(const frag8*)&As[wm * 64 + mi * 32 + lr][kc];
#pragma unroll
            for (int ni = 0; ni < 2; ++ni)
                bf[ks][ni] = *(const frag8*)&Bs[wn * 64 + ni * 32 + lr][kc];
        }
#pragma unroll
        for (int ks = 0; ks < 2; ++ks)
#pragma unroll
            for (int mi = 0; mi < 2; ++mi)
#pragma unroll
                for (int ni = 0; ni < 2; ++ni)
                    acc[mi][ni] = __builtin_amdgcn_mfma_f32_32x32x16_f16(
                        af[ks][mi], bf[ks][ni], acc[mi][ni], 0, 0, 0);
    }

    // epilogue: atomic split-K accumulate
#pragma unroll
    for (int ni = 0; ni < 2; ++ni) {
        int n = n0 + wn * 64 + ni * 32 + lr;
#pragma unroll
        for (int mi = 0; mi < 2; ++mi) {
            int mbase = mt * 128 + wm * 64 + mi * 32 + 4 * half;
#pragma unroll
            for (int reg = 0; reg < 16; ++reg) {
                int m = mbase + (reg & 3) + 8 * (reg >> 2);
                atomicAdd(&C[(long)m * 256 + n], acc[mi][ni][reg]);
            }
        }
    }
}

// --------------------------------------------------------------------------
// squash: C[(b*36+pos)][256] -> ut[n][b][8], n = ci*36+pos.
__global__ void squash_k(const float* __restrict__ C, float* __restrict__ ut) {
    int t = blockIdx.x * 256 + threadIdx.x;          // 589824 exact
    int row = t >> 5;                                 // (b*36+pos)
    int ci = t & 31;
    int b = row / 36, pos = row - b * 36;
    const float* src = C + (long)row * 256 + ci;
    float v[8]; float sn = 0.f;
#pragma unroll
    for (int i = 0; i < 8; ++i) { v[i] = src[i * 32]; sn = fmaf(v[i], v[i], sn); }
    float scale = (sn / (1.f + sn)) / sqrtf(sn);
    float* dst = ut + ((long)(ci * 36 + pos) * 512 + b) * 8;
    float4 o0 = make_float4(v[0]*scale, v[1]*scale, v[2]*scale, v[3]*scale);
    float4 o1 = make_float4(v[4]*scale, v[5]*scale, v[6]*scale, v[7]*scale);
    *(float4*)(dst) = o0;
    *(float4*)(dst + 4) = o1;
}

// --------------------------------------------------------------------------
// Phase A: priors[c,b,n,:16] = ut[n,b,:8] @ rw[c,n,:8,:16], fp16 out.
// Block = (c, 8-n group); 256 threads = 32 b x 8 n; 16 b-chunks.
// Wave-level access pattern: 8 runs of 256 B on both read and write sides.
__global__ __launch_bounds__(256) void priors_k(const float* __restrict__ ut,
                                                const float* __restrict__ rw,
                                                h16* __restrict__ priors) {
    int bid = blockIdx.x;                 // 1440 = 10 c * 144 n-groups
    int c = bid / 144, ng = bid - c * 144;
    int n0 = ng * 8;
    __shared__ float w[8][132];           // pad 132: 8 nl rows hit 8 banks
    int tid = threadIdx.x;
    for (int e = tid; e < 1024; e += 256)
        w[e >> 7][e & 127] = rw[((long)c * 1152 + n0 + (e >> 7)) * 128 + (e & 127)];
    __syncthreads();
    int nl = tid & 7, bl = tid >> 3;      // bl 0..31
    int n = n0 + nl;
    for (int ch = 0; ch < 16; ++ch) {
        int b = ch * 32 + bl;
        const float4* up = (const float4*)(ut + ((long)n * 512 + b) * 8);
        float4 ua = up[0], ub = up[1];
        float uu[8] = {ua.x, ua.y, ua.z, ua.w, ub.x, ub.y, ub.z, ub.w};
        float o[16];
#pragma unroll
        for (int j = 0; j < 16; ++j) o[j] = 0.f;
#pragma unroll
        for (int i = 0; i < 8; ++i)
#pragma unroll
            for (int j = 0; j < 16; ++j)
                o[j] = fmaf(uu[i], w[nl][i * 16 + j], o[j]);
        frag8 p0, p1;
#pragma unroll
        for (int j = 0; j < 8; ++j) { p0[j] = (h16)o[j]; p1[j] = (h16)o[j + 8]; }
        h16* dst = priors + ((long)(c * 512 + b) * 1152 + n) * 16;
        *(frag8*)dst = p0;
        *(frag8*)(dst + 8) = p1;
    }
}

// --------------------------------------------------------------------------
// Phase B: 3-iter routing from materialized fp16 priors. Block per (c,b).
__global__ __launch_bounds__(384) void routing2_k(const h16* __restrict__ priors,
                                                  float* __restrict__ vbuf) {
    int c = blockIdx.x >> 9;
    int b = blockIdx.x & 511;
    int tid = threadIdx.x;
    int wid = tid >> 6;
    int lane = tid & 63;
    __shared__ float wred[6][20];

    float pr[3][16];
#pragma unroll
    for (int r = 0; r < 3; ++r) {
        int n = tid + r * 384;
        const h16* pp = priors + ((long)(c * 512 + b) * 1152 + n) * 16;
        frag8 p0 = *(const frag8*)pp;
        frag8 p1 = *(const frag8*)(pp + 8);
#pragma unroll
        for (int o = 0; o < 8; ++o) { pr[r][o] = (float)p0[o]; pr[r][o + 8] = (float)p1[o]; }
    }

    float l0 = 0.f, l1 = 0.f, l2 = 0.f;
    float vout[16];
    for (int it = 0; it < 3; ++it) {
        float lm = fmaxf(fmaxf(l0, l1), l2);
#pragma unroll
        for (int m = 32; m >= 1; m >>= 1) lm = fmaxf(lm, __shfl_xor(lm, m));
        if (lane == 0) wred[wid][17] = lm;
        __syncthreads();
        float maxv = wred[0][17];
#pragma unroll
        for (int w = 1; w < 6; ++w) maxv = fmaxf(maxv, wred[w][17]);

        float e0 = expf(l0 - maxv), e1 = expf(l1 - maxv), e2 = expf(l2 - maxv);
        float red[17];
#pragma unroll
        for (int o = 0; o < 16; ++o)
            red[o] = fmaf(e0, pr[0][o], fmaf(e1, pr[1][o], e2 * pr[2][o]));
        red[16] = e0 + e1 + e2;
#pragma unroll
        for (int o = 0; o < 17; ++o) {
#pragma unroll
            for (int m = 32; m >= 1; m >>= 1) red[o] += __shfl_xor(red[o], m);
        }
        __syncthreads();
        if (lane == 0) {
#pragma unroll
            for (int o = 0; o < 17; ++o) wred[wid][o] = red[o];
        }
        __syncthreads();
        float sv[17];
#pragma unroll
        for (int o = 0; o < 17; ++o) {
            float tacc = wred[0][o];
#pragma unroll
            for (int w = 1; w < 6; ++w) tacc += wred[w][o];
            sv[o] = tacc;
        }
        float inv = 1.f / sv[16];
        float sn = 0.f;
#pragma unroll
        for (int o = 0; o < 16; ++o) { float s = sv[o] * inv; sn = fmaf(s, s, sn); }
        float scale = (sn / (1.f + sn)) / sqrtf(sn);
#pragma unroll
        for (int o = 0; o < 16; ++o) vout[o] = sv[o] * inv * scale;

        if (it < 2) {
            float d0 = 0.f, d1 = 0.f, d2 = 0.f;
#pragma unroll
            for (int o = 0; o < 16; ++o) {
                d0 = fmaf(pr[0][o], vout[o], d0);
                d1 = fmaf(pr[1][o], vout[o], d1);
                d2 = fmaf(pr[2][o], vout[o], d2);
            }
            l0 += d0; l1 += d1; l2 += d2;
        }
    }
    if (tid < 16) vbuf[(b * 10 + c) * 16 + tid] = vout[tid];
}

// --------------------------------------------------------------------------
__global__ void mask_k(const float* __restrict__ vbuf, float* __restrict__ out,
                       float* __restrict__ masked) {
    int b = blockIdx.x * 256 + threadIdx.x;
    if (b >= 512) return;
    const float* vp = vbuf + b * 160;
    float cls[10]; int best = 0; float bv = -1.f;
#pragma unroll
    for (int cc = 0; cc < 10; ++cc) {
        float sn = 0.f;
#pragma unroll
        for (int o = 0; o < 16; ++o) { float v = vp[cc * 16 + o]; sn = fmaf(v, v, sn); }
        cls[cc] = sqrtf(sn);
        if (cls[cc] > bv) { bv = cls[cc]; best = cc; }
    }
#pragma unroll
    for (int cc = 0; cc < 10; ++cc) {
        out[b * 10 + cc] = (cc == best) ? 1.f : 0.f;
        out[406528 + b * 10 + cc] = cls[cc];
    }
#pragma unroll
    for (int cc = 0; cc < 10; ++cc) {
        float keep = (cc == best) ? 1.f : 0.f;
#pragma unroll
        for (int o = 0; o < 16; ++o)
            masked[b * 160 + cc * 16 + o] = keep * vp[cc * 16 + o];
    }
}

// --------------------------------------------------------------------------
template <int ACT>
__global__ __launch_bounds__(256) void dec_gemm(const float* __restrict__ A,
                                                const float* __restrict__ Bw,
                                                const float* __restrict__ bias,
                                                float* __restrict__ C,
                                                int M, int N, int K) {
    __shared__ float As[16][68];
    __shared__ float Bs[16][68];
    int ntiles = (N + 63) >> 6;
    int mt = blockIdx.x / ntiles, nt = blockIdx.x - mt * ntiles;
    int m0 = mt * 64, n0 = nt * 64;
    int tid = threadIdx.x;
    int tx = tid & 15, ty = tid >> 4;
    int am = tid >> 2, ak = (tid & 3) * 4;
    int bk = tid >> 4, bn = (tid & 15) * 4;
    float acc[4][4];
#pragma unroll
    for (int i = 0; i < 4; ++i)
#pragma unroll
        for (int j = 0; j < 4; ++j) acc[i][j] = 0.f;

    for (int k0 = 0; k0 < K; k0 += 16) {
        float4 av = *(const float4*)(A + (m0 + am) * K + k0 + ak);
        float4 bv = make_float4(0.f, 0.f, 0.f, 0.f);
        if (n0 + bn < N) bv = *(const float4*)(Bw + (k0 + bk) * N + n0 + bn);
        __syncthreads();
        As[ak + 0][am] = av.x;
        As[ak + 1][am] = av.y;
        As[ak + 2][am] = av.z;
        As[ak + 3][am] = av.w;
        *(float4*)&Bs[bk][bn] = bv;
        __syncthreads();
#pragma unroll
        for (int kk = 0; kk < 16; ++kk) {
            float4 a = *(const float4*)&As[kk][ty * 4];
            float4 bb = *(const float4*)&Bs[kk][tx * 4];
            float aa[4] = {a.x, a.y, a.z, a.w};
            float bbb[4] = {bb.x, bb.y, bb.z, bb.w};
#pragma unroll
            for (int i = 0; i < 4; ++i)
#pragma unroll
                for (int j = 0; j < 4; ++j)
                    acc[i][j] = fmaf(aa[i], bbb[j], acc[i][j]);
        }
    }
#pragma unroll
    for (int i = 0; i < 4; ++i) {
        int m = m0 + ty * 4 + i;
#pragma unroll
        for (int j = 0; j < 4; ++j) {
            int n = n0 + tx * 4 + j;
            if (n < N) {
                float v = acc[i][j] + bias[n];
                if (ACT == 0) v = fmaxf(v, 0.f);
                else          v = 1.f / (1.f + expf(-v));
                C[m * N + n] = v;
            }
        }
    }
}

// --------------------------------------------------------------------------
extern "C" void kernel_launch(void* const* d_in, const int* in_sizes, int n_in,
                              void* d_out, int out_size, void* d_ws, size_t ws_size,
                              hipStream_t stream) {
    const float* x   = (const float*)d_in[0];
    const float* w1  = (const float*)d_in[1];
    const float* b1  = (const float*)d_in[2];
    const float* pw  = (const float*)d_in[3];
    const float* pb  = (const float*)d_in[4];
    const float* rw  = (const float*)d_in[5];
    const float* dw1 = (const float*)d_in[6];
    const float* db1 = (const float*)d_in[7];
    const float* dw2 = (const float*)d_in[8];
    const float* db2 = (const float*)d_in[9];
    const float* dw3 = (const float*)d_in[10];
    const float* db3 = (const float*)d_in[11];
    float* out = (float*)d_out;
    char* wsb  = (char*)d_ws;
    if (ws_size < (size_t)WS_BYTES) return;

    h16*   hhi  = (h16*)(wsb + OFFB_HHI);
    h16*   wthi = (h16*)(wsb + OFFB_WTHI);
    float* wt1  = (float*)(wsb + OFFB_WT1);
    float* Cbuf = (float*)(wsb + OFFB_C);
    h16*   pri  = (h16*)(wsb + OFFB_PRI);
    float* ut   = (float*)(wsb + OFFB_UT);
    float* vbuf = (float*)(wsb + OFFB_V);
    float* msk  = (float*)(wsb + OFFB_MSK);
    float* d1   = (float*)(wsb + OFFB_D1);
    float* d2   = (float*)(wsb + OFFB_D2);

    transpose_w1<<<81, 256, 0, stream>>>(w1, wt1);
    split_pw<<<256, 256, 0, stream>>>(pw, wthi);
    conv1_k<<<512, 448, 0, stream>>>(x, wt1, b1, hhi);
    init_C<<<18432, 256, 0, stream>>>(pb, Cbuf);
    prim_gemm_mfma<<<2304, 256, 0, stream>>>(hhi, wthi, Cbuf);
    squash_k<<<2304, 256, 0, stream>>>(Cbuf, ut);      // h region dead now
    priors_k<<<1440, 256, 0, stream>>>(ut, rw, pri);
    routing2_k<<<5120, 384, 0, stream>>>(pri, vbuf);
    mask_k<<<2, 256, 0, stream>>>(vbuf, out, msk);
    dec_gemm<0><<<64, 256, 0, stream>>>(msk, dw1, db1, d1, 512, 512, 160);
    dec_gemm<0><<<128, 256, 0, stream>>>(d1, dw2, db2, d2, 512, 1024, 512);
    dec_gemm<1><<<104, 256, 0, stream>>>(d2, dw3, db3, out + 5120, 512, 784, 1024);
}